// Round 1
// baseline (1115.563 us; speedup 1.0000x reference)
//
#include <hip/hip_runtime.h>
#include <math.h>

// Problem constants (fixed by harness: B=4, HP=WP=32, C=768, NH=24)
#define BB   4
#define TT   1024
#define CC   768
#define NH_  24
#define HS_  32

static constexpr size_t SZ = (size_t)BB * TT * CC; // 3,145,728 floats per buffer

// ---------------------------------------------------------------------------
// Kernel 1: q_shift + token-mix + small GEMM chains (per token)
// ---------------------------------------------------------------------------
__global__ __launch_bounds__(256) void mix_kernel(
    const float* __restrict__ x,
    const float* __restrict__ maa_x, const float* __restrict__ maa_w,
    const float* __restrict__ maa_k, const float* __restrict__ maa_v,
    const float* __restrict__ maa_r, const float* __restrict__ maa_g,
    const float* __restrict__ w1,    // (768,160)
    const float* __restrict__ w2,    // (5,32,768)
    const float* __restrict__ tdecay,// (768)
    const float* __restrict__ tdw1,  // (768,64)
    const float* __restrict__ tdw2,  // (64,768)
    float* __restrict__ xrO, float* __restrict__ xkO, float* __restrict__ xvO,
    float* __restrict__ xgO, float* __restrict__ decO)
{
    __shared__ float sx[CC], sxx[CC], sxxx[CC], sxw[CC];
    __shared__ float st5[160];
    __shared__ float std1[64];

    const int tok = blockIdx.x;
    const int t   = tok & (TT - 1);
    const int hh  = t >> 5;
    const int wwp = t & 31;
    const int tid = threadIdx.x;
    const float* xrow = x + (size_t)tok * CC;

    for (int c = tid; c < CC; c += 256) {
        float xc = xrow[c];
        float sh;
        if (c < 192)      sh = (wwp > 0)  ? xrow[c - CC]      : 0.f;
        else if (c < 384) sh = (wwp < 31) ? xrow[c + CC]      : 0.f;
        else if (c < 576) sh = (hh > 0)   ? xrow[c - 32 * CC] : 0.f;
        else              sh = (hh < 31)  ? xrow[c + 32 * CC] : 0.f;
        float xxv = sh - xc;
        sx[c]  = xc;
        sxx[c] = xxv;
        sxxx[c] = fmaf(xxv, maa_x[c], xc);
    }
    __syncthreads();

    // xxx @ w1 (768 -> 160), tanh
    if (tid < 160) {
        float acc = 0.f;
        #pragma unroll 4
        for (int c = 0; c < CC; ++c) acc = fmaf(sxxx[c], w1[c * 160 + tid], acc);
        st5[tid] = tanhf(acc);
    }
    __syncthreads();

    // mix einsum + 5 mixed inputs
    for (int c = tid; c < CC; c += 256) {
        float m0 = 0.f, m1 = 0.f, m2 = 0.f, m3 = 0.f, m4 = 0.f;
        #pragma unroll 8
        for (int e = 0; e < 32; ++e) {
            m0 = fmaf(st5[e],       w2[(size_t)(e)       * CC + c], m0);
            m1 = fmaf(st5[32 + e],  w2[(size_t)(32 + e)  * CC + c], m1);
            m2 = fmaf(st5[64 + e],  w2[(size_t)(64 + e)  * CC + c], m2);
            m3 = fmaf(st5[96 + e],  w2[(size_t)(96 + e)  * CC + c], m3);
            m4 = fmaf(st5[128 + e], w2[(size_t)(128 + e) * CC + c], m4);
        }
        float xc = sx[c], xxv = sxx[c];
        size_t o = (size_t)tok * CC + c;
        sxw[c] = fmaf(xxv, maa_w[c] + m0, xc);
        xkO[o] = fmaf(xxv, maa_k[c] + m1, xc);
        xvO[o] = fmaf(xxv, maa_v[c] + m2, xc);
        xrO[o] = fmaf(xxv, maa_r[c] + m3, xc);
        xgO[o] = fmaf(xxv, maa_g[c] + m4, xc);
    }
    __syncthreads();

    // decay chain: tanh(xw @ tdw1) @ tdw2 + time_decay -> exp(-exp(.))
    if (tid < 64) {
        float acc = 0.f;
        #pragma unroll 4
        for (int c = 0; c < CC; ++c) acc = fmaf(sxw[c], tdw1[c * 64 + tid], acc);
        std1[tid] = tanhf(acc);
    }
    __syncthreads();
    for (int c = tid; c < CC; c += 256) {
        float acc = tdecay[c];
        #pragma unroll 8
        for (int o = 0; o < 64; ++o) acc = fmaf(std1[o], tdw2[(size_t)o * CC + c], acc);
        decO[(size_t)tok * CC + c] = expf(-expf(acc));
    }
}

// ---------------------------------------------------------------------------
// f32 GEMM core: (4096 x 768) @ (768 x 768), 128x128 tile, BK=16, 8x8/thread
// ---------------------------------------------------------------------------
template <int ACT>
__device__ __forceinline__ void gemm_core(const float* __restrict__ A,
                                          const float* __restrict__ W,
                                          float* __restrict__ O)
{
    __shared__ float As[16][128]; // transposed: As[k][m]
    __shared__ float Bs[16][128];

    const int tid = threadIdx.x;
    const int tx = tid & 15, ty = tid >> 4;
    const int m0 = blockIdx.y * 128, n0 = blockIdx.x * 128;

    float acc[8][8];
    #pragma unroll
    for (int i = 0; i < 8; ++i)
        #pragma unroll
        for (int j = 0; j < 8; ++j) acc[i][j] = 0.f;

    const int ar = tid >> 1, ah = tid & 1;       // A: row, k-half
    const int bk = tid >> 4, bc = (tid & 15) * 8; // B: k-row, col

    for (int k0 = 0; k0 < CC; k0 += 16) {
        const float4* ap = (const float4*)(A + (size_t)(m0 + ar) * CC + k0 + ah * 8);
        float4 a0 = ap[0], a1 = ap[1];
        As[ah * 8 + 0][ar] = a0.x; As[ah * 8 + 1][ar] = a0.y;
        As[ah * 8 + 2][ar] = a0.z; As[ah * 8 + 3][ar] = a0.w;
        As[ah * 8 + 4][ar] = a1.x; As[ah * 8 + 5][ar] = a1.y;
        As[ah * 8 + 6][ar] = a1.z; As[ah * 8 + 7][ar] = a1.w;
        const float4* bp = (const float4*)(W + (size_t)(k0 + bk) * CC + n0 + bc);
        *(float4*)&Bs[bk][bc]     = bp[0];
        *(float4*)&Bs[bk][bc + 4] = bp[1];
        __syncthreads();

        #pragma unroll
        for (int kk = 0; kk < 16; ++kk) {
            float a[8], b[8];
            *(float4*)&a[0] = *(const float4*)&As[kk][ty * 8];
            *(float4*)&a[4] = *(const float4*)&As[kk][ty * 8 + 4];
            *(float4*)&b[0] = *(const float4*)&Bs[kk][tx * 8];
            *(float4*)&b[4] = *(const float4*)&Bs[kk][tx * 8 + 4];
            #pragma unroll
            for (int i = 0; i < 8; ++i)
                #pragma unroll
                for (int j = 0; j < 8; ++j)
                    acc[i][j] = fmaf(a[i], b[j], acc[i][j]);
        }
        __syncthreads();
    }

    #pragma unroll
    for (int i = 0; i < 8; ++i) {
        float out[8];
        #pragma unroll
        for (int j = 0; j < 8; ++j) {
            float vv = acc[i][j];
            if (ACT == 1) vv = vv / (1.f + expf(-vv)); // silu
            out[j] = vv;
        }
        float* op = O + (size_t)(m0 + ty * 8 + i) * CC + n0 + tx * 8;
        *(float4*)&op[0] = *(float4*)&out[0];
        *(float4*)&op[4] = *(float4*)&out[4];
    }
}

__global__ __launch_bounds__(256) void gemm_rkvg(
    const float* __restrict__ xr, const float* __restrict__ xk,
    const float* __restrict__ xv, const float* __restrict__ xg,
    const float* __restrict__ Wr, const float* __restrict__ Wk,
    const float* __restrict__ Wv, const float* __restrict__ Wg,
    float* __restrict__ r, float* __restrict__ k,
    float* __restrict__ v, float* __restrict__ g)
{
    switch (blockIdx.z) {
        case 0:  gemm_core<0>(xr, Wr, r); break;
        case 1:  gemm_core<0>(xk, Wk, k); break;
        case 2:  gemm_core<0>(xv, Wv, v); break;
        default: gemm_core<1>(xg, Wg, g); break;
    }
}

__global__ __launch_bounds__(256) void gemm_single(
    const float* __restrict__ A, const float* __restrict__ W, float* __restrict__ O)
{
    gemm_core<0>(A, W, O);
}

// ---------------------------------------------------------------------------
// Kernel 3: WKV6 scan. One wave per (b,h). Lane owns column i (i = lane&31);
// half-wave owns 16 of the 32 j rows. Chunked LDS staging of r/k/v/dec.
// ---------------------------------------------------------------------------
__global__ __launch_bounds__(64) void wkv_scan(
    const float* __restrict__ r, const float* __restrict__ k,
    const float* __restrict__ v, const float* __restrict__ dec,
    const float* __restrict__ u, float* __restrict__ y)
{
    __shared__ float rl[64][32], kl[64][32], vl[64][32], dl[64][32];

    const int bh = blockIdx.x;
    const int b = bh / NH_, h = bh % NH_;
    const int tid = threadIdx.x;
    const int i = tid & 31;
    const int jbase = (tid >> 5) * 16;

    float ureg[16];
    #pragma unroll
    for (int jj = 0; jj < 16; ++jj) ureg[jj] = u[h * HS_ + jbase + jj];

    float s[16];
    #pragma unroll
    for (int jj = 0; jj < 16; ++jj) s[jj] = 0.f;

    const size_t base0 = ((size_t)b * TT) * CC + (size_t)h * HS_;

    for (int tc = 0; tc < TT; tc += 64) {
        for (int idx = tid; idx < 64 * 32; idx += 64) {
            int ttt = idx >> 5, cc = idx & 31;
            size_t gp = base0 + (size_t)(tc + ttt) * CC + cc;
            rl[ttt][cc] = r[gp];
            kl[ttt][cc] = k[gp];
            vl[ttt][cc] = v[gp];
            dl[ttt][cc] = dec[gp];
        }
        __syncthreads();

        for (int t = 0; t < 64; ++t) {
            float vi = vl[t][i];
            float partial = 0.f;
            #pragma unroll
            for (int q = 0; q < 4; ++q) {
                float4 r4 = *(const float4*)&rl[t][jbase + q * 4];
                float4 k4 = *(const float4*)&kl[t][jbase + q * 4];
                float4 d4 = *(const float4*)&dl[t][jbase + q * 4];
                const float* rp = (const float*)&r4;
                const float* kp = (const float*)&k4;
                const float* dp = (const float*)&d4;
                #pragma unroll
                for (int w4 = 0; w4 < 4; ++w4) {
                    int jj = q * 4 + w4;
                    float kv = kp[w4] * vi;
                    partial = fmaf(rp[w4], fmaf(ureg[jj], kv, s[jj]), partial);
                    s[jj] = fmaf(dp[w4], s[jj], kv);
                }
            }
            partial += __shfl_xor(partial, 32);
            if (tid < 32) y[base0 + (size_t)(tc + t) * CC + i] = partial;
        }
        __syncthreads();
    }
}

// ---------------------------------------------------------------------------
// Kernel 4: LayerNorm(y) * g
// ---------------------------------------------------------------------------
__global__ __launch_bounds__(256) void ln_gate(
    const float* __restrict__ y, const float* __restrict__ g,
    const float* __restrict__ lnw, const float* __restrict__ lnb,
    float* __restrict__ z)
{
    __shared__ float sy[CC];
    __shared__ float rbuf[8];
    __shared__ float stats[2];

    const int row = blockIdx.x, tid = threadIdx.x;
    const float* yr = y + (size_t)row * CC;

    float s1 = 0.f, s2 = 0.f;
    #pragma unroll
    for (int q = 0; q < 3; ++q) {
        int c = tid + q * 256;
        float vv = yr[c];
        sy[c] = vv;
        s1 += vv;
        s2 += vv * vv;
    }
    #pragma unroll
    for (int off = 32; off > 0; off >>= 1) {
        s1 += __shfl_down(s1, off);
        s2 += __shfl_down(s2, off);
    }
    const int wid = tid >> 6;
    if ((tid & 63) == 0) { rbuf[wid] = s1; rbuf[4 + wid] = s2; }
    __syncthreads();
    if (tid == 0) {
        float S1 = rbuf[0] + rbuf[1] + rbuf[2] + rbuf[3];
        float S2 = rbuf[4] + rbuf[5] + rbuf[6] + rbuf[7];
        float mu = S1 / (float)CC;
        float var = S2 / (float)CC - mu * mu;
        stats[0] = mu;
        stats[1] = rsqrtf(var + 1e-5f);
    }
    __syncthreads();
    const float mu = stats[0], rstd = stats[1];
    const float* gr = g + (size_t)row * CC;
    float* zr = z + (size_t)row * CC;
    #pragma unroll
    for (int q = 0; q < 3; ++q) {
        int c = tid + q * 256;
        zr[c] = fmaf((sy[c] - mu) * rstd, lnw[c], lnb[c]) * gr[c];
    }
}

// ---------------------------------------------------------------------------
extern "C" void kernel_launch(void* const* d_in, const int* in_sizes, int n_in,
                              void* d_out, int out_size, void* d_ws, size_t ws_size,
                              hipStream_t stream)
{
    const float* x      = (const float*)d_in[0];
    const float* maa_x  = (const float*)d_in[1];
    const float* maa_w  = (const float*)d_in[2];
    const float* maa_k  = (const float*)d_in[3];
    const float* maa_v  = (const float*)d_in[4];
    const float* maa_r  = (const float*)d_in[5];
    const float* maa_g  = (const float*)d_in[6];
    const float* w1     = (const float*)d_in[7];
    const float* w2     = (const float*)d_in[8];
    const float* tdec   = (const float*)d_in[9];
    const float* tdw1   = (const float*)d_in[10];
    const float* tdw2   = (const float*)d_in[11];
    const float* faaaa  = (const float*)d_in[12];
    const float* Wr     = (const float*)d_in[13];
    const float* Wk     = (const float*)d_in[14];
    const float* Wv     = (const float*)d_in[15];
    const float* Wg     = (const float*)d_in[16];
    const float* Wo     = (const float*)d_in[17];
    const float* lnw    = (const float*)d_in[18];
    const float* lnb    = (const float*)d_in[19];

    float* ws  = (float*)d_ws;
    float* xr  = ws + 0 * SZ;
    float* xk  = ws + 1 * SZ;
    float* xv  = ws + 2 * SZ;
    float* xg  = ws + 3 * SZ;
    float* dec = ws + 4 * SZ;
    float* r_  = ws + 5 * SZ;
    float* k_  = ws + 6 * SZ;
    float* v_  = ws + 7 * SZ;
    float* g_  = ws + 8 * SZ;
    float* y_  = xr;  // xr dead after gemm_rkvg
    float* z_  = xk;  // xk dead after gemm_rkvg

    mix_kernel<<<BB * TT, 256, 0, stream>>>(x, maa_x, maa_w, maa_k, maa_v, maa_r,
                                            maa_g, w1, w2, tdec, tdw1, tdw2,
                                            xr, xk, xv, xg, dec);

    gemm_rkvg<<<dim3(6, 32, 4), 256, 0, stream>>>(xr, xk, xv, xg,
                                                  Wr, Wk, Wv, Wg,
                                                  r_, k_, v_, g_);

    wkv_scan<<<BB * NH_, 64, 0, stream>>>(r_, k_, v_, dec, faaaa, y_);

    ln_gate<<<BB * TT, 256, 0, stream>>>(y_, g_, lnw, lnb, z_);

    gemm_single<<<dim3(6, 32, 1), 256, 0, stream>>>(z_, Wo, (float*)d_out);
}

// Round 3
// 489.201 us; speedup vs baseline: 2.2804x; 2.2804x over previous
//
#include <hip/hip_runtime.h>
#include <math.h>

#define BB   4
#define TT   1024
#define CC   768
#define NH_  24
#define HS_  32

static constexpr size_t SZ = (size_t)BB * TT * CC; // 3,145,728 elements

typedef __attribute__((ext_vector_type(8))) __bf16 bf16x8;
typedef __attribute__((ext_vector_type(4))) float  f32x4;

__device__ __forceinline__ unsigned short f2bf(float f) {
    unsigned u = __float_as_uint(f);
    unsigned r = (u + 0x7FFFu + ((u >> 16) & 1u)) >> 16;
    return (unsigned short)r;
}
__device__ __forceinline__ float bf2f(unsigned short h) {
    return __uint_as_float(((unsigned)h) << 16);
}

// ---------------------------------------------------------------------------
// Weight prep: transpose + f32->bf16 cast. dst is (C x R) row-major = N x K.
// ---------------------------------------------------------------------------
struct TDesc { const float* src; unsigned short* dst; int R, C; };
struct TArgs { TDesc d[8]; };

__global__ __launch_bounds__(256) void transpose_cast(TArgs a)
{
    __shared__ float tile[32][33];
    TDesc t = a.d[blockIdx.z];
    const int tx0 = blockIdx.x * 32, ty0 = blockIdx.y * 32;
    if (tx0 >= t.C || ty0 >= t.R) return;
    const int tx = threadIdx.x & 31, ty = threadIdx.x >> 5;
    #pragma unroll
    for (int dy = 0; dy < 4; ++dy) {
        int rr = ty0 + ty + dy * 8, cc = tx0 + tx;
        tile[ty + dy * 8][tx] = (rr < t.R && cc < t.C) ? t.src[(size_t)rr * t.C + cc] : 0.f;
    }
    __syncthreads();
    #pragma unroll
    for (int dy = 0; dy < 4; ++dy) {
        int cc = tx0 + ty + dy * 8, rr = ty0 + tx;
        if (cc < t.C && rr < t.R)
            t.dst[(size_t)cc * t.R + rr] = f2bf(tile[tx][ty + dy * 8]);
    }
}

// Build block-diagonal W2^T: (3840 x 160) bf16. W2t[n][e] = w2[k][e-32k][c]
// when e/32 == k (k=n/768, c=n%768), else 0.
__global__ __launch_bounds__(192) void w2fill(const float* __restrict__ w2,
                                              unsigned short* __restrict__ W2t)
{
    const int n = blockIdx.x;
    const int e = threadIdx.x;
    if (e >= 160) return;
    const int kk = n / 768;
    const int c  = n - kk * 768;
    unsigned short val = 0;
    if ((e >> 5) == kk) val = f2bf(w2[(size_t)e * 768 + c]);
    W2t[(size_t)n * 160 + e] = val;
}

// ---------------------------------------------------------------------------
// shift: xx = qshift(x)-x (f32), xxx = bf16(x + xx*maa_x)
// ---------------------------------------------------------------------------
__global__ __launch_bounds__(256) void shift_kernel(
    const float* __restrict__ x, const float* __restrict__ maa_x,
    float* __restrict__ xxO, unsigned short* __restrict__ xxxO)
{
    const int tok = blockIdx.x;
    const int t   = tok & (TT - 1);
    const int hh  = t >> 5;
    const int wp  = t & 31;
    const int tid = threadIdx.x;
    const float* xrow = x + (size_t)tok * CC;
    for (int c = tid; c < CC; c += 256) {
        float xc = xrow[c];
        float sh;
        if (c < 192)      sh = (wp > 0)  ? xrow[c - CC]      : 0.f;
        else if (c < 384) sh = (wp < 31) ? xrow[c + CC]      : 0.f;
        else if (c < 576) sh = (hh > 0)  ? xrow[c - 32 * CC] : 0.f;
        else              sh = (hh < 31) ? xrow[c + 32 * CC] : 0.f;
        float xxv = sh - xc;
        size_t o = (size_t)tok * CC + c;
        xxO[o]  = xxv;
        xxxO[o] = f2bf(fmaf(xxv, maa_x[c], xc));
    }
}

// ---------------------------------------------------------------------------
// Generic bf16 MFMA GEMM: O = epi( A(M x K) @ Wt(N x K)^T ), 64x64 tile,
// 4 waves (each 32x32 = 2x2 frags of 16x16x32), BK=32, LDS pad +8 bf16.
// ---------------------------------------------------------------------------
template<int KDIM, class Epi>
__device__ __forceinline__ void gemm_core(const unsigned short* __restrict__ A,
                                          const unsigned short* __restrict__ W,
                                          int N, const Epi& epi)
{
    __shared__ __align__(16) unsigned short As[64][40];
    __shared__ __align__(16) unsigned short Bs[64][40];

    const int tid  = threadIdx.x;
    const int lane = tid & 63;
    const int wv   = tid >> 6;
    const int wm   = (wv >> 1) * 32, wn = (wv & 1) * 32;
    const int m0   = blockIdx.y * 64, n0 = blockIdx.x * 64;
    const int srow = tid >> 2, scb = (tid & 3) * 8;
    const int l15  = lane & 15, kb8 = (lane >> 4) * 8;

    f32x4 acc[2][2];
    #pragma unroll
    for (int a = 0; a < 2; ++a)
        #pragma unroll
        for (int b = 0; b < 2; ++b)
            #pragma unroll
            for (int e = 0; e < 4; ++e) acc[a][b][e] = 0.f;

    const unsigned short* aP = A + (size_t)(m0 + srow) * KDIM + scb;
    const unsigned short* bP = W + (size_t)(n0 + srow) * KDIM + scb;
    const bool bvalid = (n0 + srow) < N;

    for (int k0 = 0; k0 < KDIM; k0 += 32) {
        uint4 av = *(const uint4*)(aP + k0);
        uint4 bw = make_uint4(0u, 0u, 0u, 0u);
        if (bvalid) bw = *(const uint4*)(bP + k0);
        *(uint4*)&As[srow][scb] = av;
        *(uint4*)&Bs[srow][scb] = bw;
        __syncthreads();

        bf16x8 a0 = *(const bf16x8*)&As[wm + l15][kb8];
        bf16x8 a1 = *(const bf16x8*)&As[wm + 16 + l15][kb8];
        bf16x8 b0 = *(const bf16x8*)&Bs[wn + l15][kb8];
        bf16x8 b1 = *(const bf16x8*)&Bs[wn + 16 + l15][kb8];
        acc[0][0] = __builtin_amdgcn_mfma_f32_16x16x32_bf16(a0, b0, acc[0][0], 0, 0, 0);
        acc[0][1] = __builtin_amdgcn_mfma_f32_16x16x32_bf16(a0, b1, acc[0][1], 0, 0, 0);
        acc[1][0] = __builtin_amdgcn_mfma_f32_16x16x32_bf16(a1, b0, acc[1][0], 0, 0, 0);
        acc[1][1] = __builtin_amdgcn_mfma_f32_16x16x32_bf16(a1, b1, acc[1][1], 0, 0, 0);
        __syncthreads();
    }

    const int rb_ = m0 + wm + (lane >> 4) * 4;
    #pragma unroll
    for (int mi = 0; mi < 2; ++mi)
        #pragma unroll
        for (int ni = 0; ni < 2; ++ni) {
            int col = n0 + wn + ni * 16 + l15;
            if (col < N) {
                #pragma unroll
                for (int j = 0; j < 4; ++j)
                    epi(rb_ + mi * 16 + j, col, acc[mi][ni][j]);
            }
        }
}

// Epilogues ----------------------------------------------------------------
struct EpiTanh {  // bf16 out, tanh
    unsigned short* O; int ldo;
    __device__ void operator()(int r, int c, float v) const {
        O[(size_t)r * ldo + c] = f2bf(tanhf(v));
    }
};
struct EpiF32 {   // f32 out (ld = 768)
    float* O;
    __device__ void operator()(int r, int c, float v) const {
        O[(size_t)r * 768 + c] = v;
    }
};
struct EpiDec {   // dec = exp(-exp(time_decay + v)), f32 out
    const float* td; float* O;
    __device__ void operator()(int r, int c, float v) const {
        O[(size_t)r * 768 + c] = expf(-expf(td[c] + v));
    }
};
struct EpiMix {   // 5-way demux: out_k = bf16(x + xx*(maa_k + v))
    const float* px; const float* pxx;
    const float* maa[5];
    unsigned short* outs[5];
    __device__ void operator()(int r, int c, float v) const {
        int kk = c / 768;
        int cc = c - kk * 768;
        size_t o = (size_t)r * 768 + cc;
        outs[kk][o] = f2bf(fmaf(pxx[o], maa[kk][cc] + v, px[o]));
    }
};
struct EpiRKVG {  // bf16 out, optional silu
    unsigned short* O; bool silu;
    __device__ void operator()(int r, int c, float v) const {
        if (silu) v = v / (1.f + expf(-v));
        O[(size_t)r * 768 + c] = f2bf(v);
    }
};

template<int KDIM, class Epi>
__global__ __launch_bounds__(256) void gemm_one(const unsigned short* __restrict__ A,
                                                const unsigned short* __restrict__ W,
                                                int N, Epi epi)
{
    gemm_core<KDIM>(A, W, N, epi);
}

struct QuadArgs {
    const unsigned short* A[4];
    const unsigned short* W[4];
    unsigned short* O[4];
};
__global__ __launch_bounds__(256) void gemm_quad768(QuadArgs q)
{
    const int z = blockIdx.z;
    EpiRKVG e{q.O[z], z == 3};
    gemm_core<768>(q.A[z], q.W[z], 768, e);
}

// ---------------------------------------------------------------------------
// WKV6 scan: one wave per (b,h). Lane owns column i (lane&31); half-wave
// owns 16 of 32 j rows. f32 state; bf16 r/k/v inputs, f32 dec.
// ---------------------------------------------------------------------------
__global__ __launch_bounds__(64) void wkv_scan(
    const unsigned short* __restrict__ r, const unsigned short* __restrict__ k,
    const unsigned short* __restrict__ v, const float* __restrict__ dec,
    const float* __restrict__ u, float* __restrict__ y)
{
    __shared__ __align__(16) float rl[64][32], kl[64][32], vl[64][32], dl[64][32];

    const int bh = blockIdx.x;
    const int b = bh / NH_, h = bh % NH_;
    const int tid = threadIdx.x;
    const int i = tid & 31;
    const int jbase = (tid >> 5) * 16;

    float ureg[16];
    #pragma unroll
    for (int jj = 0; jj < 16; ++jj) ureg[jj] = u[h * HS_ + jbase + jj];

    float s[16];
    #pragma unroll
    for (int jj = 0; jj < 16; ++jj) s[jj] = 0.f;

    const size_t base0 = ((size_t)b * TT) * CC + (size_t)h * HS_;
    const int lrow = tid >> 2, lq = (tid & 3) * 8;
    const int drow = tid >> 3, dq = (tid & 7) * 4;

    for (int tc = 0; tc < TT; tc += 64) {
        #pragma unroll
        for (int rr = 0; rr < 4; ++rr) {
            int row = rr * 16 + lrow;
            size_t gp = base0 + (size_t)(tc + row) * CC + lq;
            uint4 rv = *(const uint4*)(r + gp);
            uint4 kv = *(const uint4*)(k + gp);
            uint4 vv = *(const uint4*)(v + gp);
            const unsigned short* rp = (const unsigned short*)&rv;
            const unsigned short* kp = (const unsigned short*)&kv;
            const unsigned short* vp = (const unsigned short*)&vv;
            #pragma unroll
            for (int e = 0; e < 8; ++e) {
                rl[row][lq + e] = bf2f(rp[e]);
                kl[row][lq + e] = bf2f(kp[e]);
                vl[row][lq + e] = bf2f(vp[e]);
            }
        }
        #pragma unroll
        for (int rr = 0; rr < 8; ++rr) {
            int row = rr * 8 + drow;
            *(float4*)&dl[row][dq] = *(const float4*)(dec + base0 + (size_t)(tc + row) * CC + dq);
        }
        __syncthreads();

        for (int t = 0; t < 64; ++t) {
            float vi = vl[t][i];
            float partial = 0.f;
            #pragma unroll
            for (int q = 0; q < 4; ++q) {
                float4 r4 = *(const float4*)&rl[t][jbase + q * 4];
                float4 k4 = *(const float4*)&kl[t][jbase + q * 4];
                float4 d4 = *(const float4*)&dl[t][jbase + q * 4];
                const float* rp = (const float*)&r4;
                const float* kp = (const float*)&k4;
                const float* dp = (const float*)&d4;
                #pragma unroll
                for (int w4 = 0; w4 < 4; ++w4) {
                    int jj = q * 4 + w4;
                    float kv = kp[w4] * vi;
                    partial = fmaf(rp[w4], fmaf(ureg[jj], kv, s[jj]), partial);
                    s[jj] = fmaf(dp[w4], s[jj], kv);
                }
            }
            partial += __shfl_xor(partial, 32);
            if (tid < 32) y[base0 + (size_t)(tc + t) * CC + i] = partial;
        }
        __syncthreads();
    }
}

// ---------------------------------------------------------------------------
// LayerNorm(y) * g -> bf16 z
// ---------------------------------------------------------------------------
__global__ __launch_bounds__(256) void ln_gate(
    const float* __restrict__ y, const unsigned short* __restrict__ g,
    const float* __restrict__ lnw, const float* __restrict__ lnb,
    unsigned short* __restrict__ z)
{
    __shared__ float sy[CC];
    __shared__ float rbuf[8];
    __shared__ float stats[2];

    const int row = blockIdx.x, tid = threadIdx.x;
    const float* yr = y + (size_t)row * CC;

    float s1 = 0.f, s2 = 0.f;
    #pragma unroll
    for (int q = 0; q < 3; ++q) {
        int c = tid + q * 256;
        float vv = yr[c];
        sy[c] = vv;
        s1 += vv;
        s2 += vv * vv;
    }
    #pragma unroll
    for (int off = 32; off > 0; off >>= 1) {
        s1 += __shfl_down(s1, off);
        s2 += __shfl_down(s2, off);
    }
    const int wid = tid >> 6;
    if ((tid & 63) == 0) { rbuf[wid] = s1; rbuf[4 + wid] = s2; }
    __syncthreads();
    if (tid == 0) {
        float S1 = rbuf[0] + rbuf[1] + rbuf[2] + rbuf[3];
        float S2 = rbuf[4] + rbuf[5] + rbuf[6] + rbuf[7];
        float mu = S1 / (float)CC;
        float var = S2 / (float)CC - mu * mu;
        stats[0] = mu;
        stats[1] = rsqrtf(var + 1e-5f);
    }
    __syncthreads();
    const float mu = stats[0], rstd = stats[1];
    const unsigned short* gr = g + (size_t)row * CC;
    unsigned short* zr = z + (size_t)row * CC;
    #pragma unroll
    for (int q = 0; q < 3; ++q) {
        int c = tid + q * 256;
        zr[c] = f2bf(fmaf((sy[c] - mu) * rstd, lnw[c], lnb[c]) * bf2f(gr[c]));
    }
}

// ---------------------------------------------------------------------------
extern "C" void kernel_launch(void* const* d_in, const int* in_sizes, int n_in,
                              void* d_out, int out_size, void* d_ws, size_t ws_size,
                              hipStream_t stream)
{
    const float* x      = (const float*)d_in[0];
    const float* maa_x  = (const float*)d_in[1];
    const float* maa_w  = (const float*)d_in[2];
    const float* maa_k  = (const float*)d_in[3];
    const float* maa_v  = (const float*)d_in[4];
    const float* maa_r  = (const float*)d_in[5];
    const float* maa_g  = (const float*)d_in[6];
    const float* w1     = (const float*)d_in[7];
    const float* w2     = (const float*)d_in[8];
    const float* tdec   = (const float*)d_in[9];
    const float* tdw1   = (const float*)d_in[10];
    const float* tdw2   = (const float*)d_in[11];
    const float* faaaa  = (const float*)d_in[12];
    const float* Wr     = (const float*)d_in[13];
    const float* Wk     = (const float*)d_in[14];
    const float* Wv     = (const float*)d_in[15];
    const float* Wg     = (const float*)d_in[16];
    const float* Wo     = (const float*)d_in[17];
    const float* lnw    = (const float*)d_in[18];
    const float* lnb    = (const float*)d_in[19];

    char* base = (char*)d_ws;
    size_t off = 0;
    auto alloc = [&](size_t bytes) -> char* {
        char* p = base + off;
        off = (off + bytes + 255) & ~(size_t)255;
        return p;
    };

    float*          xx   = (float*)alloc(SZ * 4);           // later reused as y
    float*          decb = (float*)alloc(SZ * 4);
    unsigned short* xxx  = (unsigned short*)alloc(SZ * 2);  // later reused as z
    unsigned short* xw   = (unsigned short*)alloc(SZ * 2);
    unsigned short* xk   = (unsigned short*)alloc(SZ * 2);
    unsigned short* xv   = (unsigned short*)alloc(SZ * 2);
    unsigned short* xr   = (unsigned short*)alloc(SZ * 2);
    unsigned short* xg   = (unsigned short*)alloc(SZ * 2);
    unsigned short* rb   = (unsigned short*)alloc(SZ * 2);
    unsigned short* kb   = (unsigned short*)alloc(SZ * 2);
    unsigned short* vb   = (unsigned short*)alloc(SZ * 2);
    unsigned short* gb   = (unsigned short*)alloc(SZ * 2);
    unsigned short* t5   = (unsigned short*)alloc((size_t)4096 * 160 * 2);
    unsigned short* d1   = (unsigned short*)alloc((size_t)4096 * 64 * 2);
    unsigned short* w1t  = (unsigned short*)alloc((size_t)160 * 768 * 2);
    unsigned short* w2t  = (unsigned short*)alloc((size_t)3840 * 160 * 2);
    unsigned short* wrt  = (unsigned short*)alloc((size_t)768 * 768 * 2);
    unsigned short* wkt  = (unsigned short*)alloc((size_t)768 * 768 * 2);
    unsigned short* wvt  = (unsigned short*)alloc((size_t)768 * 768 * 2);
    unsigned short* wgt  = (unsigned short*)alloc((size_t)768 * 768 * 2);
    unsigned short* wot  = (unsigned short*)alloc((size_t)768 * 768 * 2);
    unsigned short* td1t = (unsigned short*)alloc((size_t)64 * 768 * 2);
    unsigned short* td2t = (unsigned short*)alloc((size_t)768 * 64 * 2);
    float*          y    = xx;   // xx dead after mixall epilogue
    unsigned short* z    = xxx;  // xxx dead after t5 GEMM

    // 1) weight prep
    TArgs ta = {{
        { w1,   w1t,  768, 160 },
        { Wr,   wrt,  768, 768 },
        { Wk,   wkt,  768, 768 },
        { Wv,   wvt,  768, 768 },
        { Wg,   wgt,  768, 768 },
        { Wo,   wot,  768, 768 },
        { tdw1, td1t, 768, 64  },
        { tdw2, td2t, 64,  768 },
    }};
    transpose_cast<<<dim3(24, 24, 8), 256, 0, stream>>>(ta);
    w2fill<<<3840, 192, 0, stream>>>(w2, w2t);

    // 2) shift + xxx
    shift_kernel<<<BB * TT, 256, 0, stream>>>(x, maa_x, xx, xxx);

    // 3) t5 = tanh(xxx @ w1)           (M=4096, K=768, N=160)
    gemm_one<768, EpiTanh><<<dim3(3, 64), 256, 0, stream>>>(xxx, w1t, 160, EpiTanh{t5, 160});

    // 4) mixall: t5 @ blockdiag(w2)    (K=160, N=3840) + demux epilogue
    EpiMix em{ x, xx,
               { maa_w, maa_k, maa_v, maa_r, maa_g },
               { xw, xk, xv, xr, xg } };
    gemm_one<160, EpiMix><<<dim3(60, 64), 256, 0, stream>>>(t5, w2t, 3840, em);

    // 5) d1 = tanh(xw @ tdw1)          (K=768, N=64)
    gemm_one<768, EpiTanh><<<dim3(1, 64), 256, 0, stream>>>(xw, td1t, 64, EpiTanh{d1, 64});

    // 6) dec = exp(-exp(tdecay + d1 @ tdw2))   (K=64, N=768)
    gemm_one<64, EpiDec><<<dim3(12, 64), 256, 0, stream>>>(d1, td2t, 768, EpiDec{tdec, decb});

    // 7) r,k,v,g GEMMs (bf16 out, silu on g)
    QuadArgs qa = {{ xr, xk, xv, xg }, { wrt, wkt, wvt, wgt }, { rb, kb, vb, gb }};
    gemm_quad768<<<dim3(12, 64, 4), 256, 0, stream>>>(qa);

    // 8) WKV scan (f32 state, f32 dec)
    wkv_scan<<<BB * NH_, 64, 0, stream>>>(rb, kb, vb, decb, faaaa, y);

    // 9) LayerNorm * gate -> z (bf16)
    ln_gate<<<BB * TT, 256, 0, stream>>>(y, gb, lnw, lnb, z);

    // 10) out = z @ Wo (f32 out)
    gemm_one<768, EpiF32><<<dim3(12, 64), 256, 0, stream>>>(z, wot, 768, EpiF32{(float*)d_out});
}

// Round 4
// 321.674 us; speedup vs baseline: 3.4680x; 1.5208x over previous
//
#include <hip/hip_runtime.h>
#include <math.h>

#define BB   4
#define TT   1024
#define CC   768
#define NH_  24
#define HS_  32

static constexpr size_t SZ = (size_t)BB * TT * CC; // 3,145,728 elements

typedef __attribute__((ext_vector_type(8))) __bf16 bf16x8;
typedef __attribute__((ext_vector_type(4))) float  f32x4;

__device__ __forceinline__ unsigned short f2bf(float f) {
    unsigned u = __float_as_uint(f);
    unsigned r = (u + 0x7FFFu + ((u >> 16) & 1u)) >> 16;
    return (unsigned short)r;
}
__device__ __forceinline__ float bf2f(unsigned short h) {
    return __uint_as_float(((unsigned)h) << 16);
}

// ---------------------------------------------------------------------------
// Weight prep: transpose + f32->bf16 cast. dst is (C x R) row-major = N x K.
// ---------------------------------------------------------------------------
struct TDesc { const float* src; unsigned short* dst; int R, C; };
struct TArgs { TDesc d[8]; };

__global__ __launch_bounds__(256) void transpose_cast(TArgs a)
{
    __shared__ float tile[32][33];
    TDesc t = a.d[blockIdx.z];
    const int tx0 = blockIdx.x * 32, ty0 = blockIdx.y * 32;
    if (tx0 >= t.C || ty0 >= t.R) return;
    const int tx = threadIdx.x & 31, ty = threadIdx.x >> 5;
    #pragma unroll
    for (int dy = 0; dy < 4; ++dy) {
        int rr = ty0 + ty + dy * 8, cc = tx0 + tx;
        tile[ty + dy * 8][tx] = (rr < t.R && cc < t.C) ? t.src[(size_t)rr * t.C + cc] : 0.f;
    }
    __syncthreads();
    #pragma unroll
    for (int dy = 0; dy < 4; ++dy) {
        int cc = tx0 + ty + dy * 8, rr = ty0 + tx;
        if (cc < t.C && rr < t.R)
            t.dst[(size_t)cc * t.R + rr] = f2bf(tile[tx][ty + dy * 8]);
    }
}

// Build block-diagonal W2^T: (3840 x 160) bf16.
__global__ __launch_bounds__(192) void w2fill(const float* __restrict__ w2,
                                              unsigned short* __restrict__ W2t)
{
    const int n = blockIdx.x;
    const int e = threadIdx.x;
    if (e >= 160) return;
    const int kk = n / 768;
    const int c  = n - kk * 768;
    unsigned short val = 0;
    if ((e >> 5) == kk) val = f2bf(w2[(size_t)e * 768 + c]);
    W2t[(size_t)n * 160 + e] = val;
}

// ---------------------------------------------------------------------------
// shift: xx = qshift(x)-x (f32), xxx = bf16(x + xx*maa_x)
// ---------------------------------------------------------------------------
__global__ __launch_bounds__(256) void shift_kernel(
    const float* __restrict__ x, const float* __restrict__ maa_x,
    float* __restrict__ xxO, unsigned short* __restrict__ xxxO)
{
    const int tok = blockIdx.x;
    const int t   = tok & (TT - 1);
    const int hh  = t >> 5;
    const int wp  = t & 31;
    const int tid = threadIdx.x;
    const float* xrow = x + (size_t)tok * CC;
    for (int c = tid; c < CC; c += 256) {
        float xc = xrow[c];
        float sh;
        if (c < 192)      sh = (wp > 0)  ? xrow[c - CC]      : 0.f;
        else if (c < 384) sh = (wp < 31) ? xrow[c + CC]      : 0.f;
        else if (c < 576) sh = (hh > 0)  ? xrow[c - 32 * CC] : 0.f;
        else              sh = (hh < 31) ? xrow[c + 32 * CC] : 0.f;
        float xxv = sh - xc;
        size_t o = (size_t)tok * CC + c;
        xxO[o]  = xxv;
        xxxO[o] = f2bf(fmaf(xxv, maa_x[c], xc));
    }
}

// ---------------------------------------------------------------------------
// Generic bf16 MFMA GEMM: O = epi( A(M x K) @ Wt(N x K)^T ), 64x64 tile.
// ---------------------------------------------------------------------------
template<int KDIM, class Epi>
__device__ __forceinline__ void gemm_core(const unsigned short* __restrict__ A,
                                          const unsigned short* __restrict__ W,
                                          int N, const Epi& epi)
{
    __shared__ __align__(16) unsigned short As[64][40];
    __shared__ __align__(16) unsigned short Bs[64][40];

    const int tid  = threadIdx.x;
    const int lane = tid & 63;
    const int wv   = tid >> 6;
    const int wm   = (wv >> 1) * 32, wn = (wv & 1) * 32;
    const int m0   = blockIdx.y * 64, n0 = blockIdx.x * 64;
    const int srow = tid >> 2, scb = (tid & 3) * 8;
    const int l15  = lane & 15, kb8 = (lane >> 4) * 8;

    f32x4 acc[2][2];
    #pragma unroll
    for (int a = 0; a < 2; ++a)
        #pragma unroll
        for (int b = 0; b < 2; ++b)
            #pragma unroll
            for (int e = 0; e < 4; ++e) acc[a][b][e] = 0.f;

    const unsigned short* aP = A + (size_t)(m0 + srow) * KDIM + scb;
    const unsigned short* bP = W + (size_t)(n0 + srow) * KDIM + scb;
    const bool bvalid = (n0 + srow) < N;

    for (int k0 = 0; k0 < KDIM; k0 += 32) {
        uint4 av = *(const uint4*)(aP + k0);
        uint4 bw = make_uint4(0u, 0u, 0u, 0u);
        if (bvalid) bw = *(const uint4*)(bP + k0);
        *(uint4*)&As[srow][scb] = av;
        *(uint4*)&Bs[srow][scb] = bw;
        __syncthreads();

        bf16x8 a0 = *(const bf16x8*)&As[wm + l15][kb8];
        bf16x8 a1 = *(const bf16x8*)&As[wm + 16 + l15][kb8];
        bf16x8 b0 = *(const bf16x8*)&Bs[wn + l15][kb8];
        bf16x8 b1 = *(const bf16x8*)&Bs[wn + 16 + l15][kb8];
        acc[0][0] = __builtin_amdgcn_mfma_f32_16x16x32_bf16(a0, b0, acc[0][0], 0, 0, 0);
        acc[0][1] = __builtin_amdgcn_mfma_f32_16x16x32_bf16(a0, b1, acc[0][1], 0, 0, 0);
        acc[1][0] = __builtin_amdgcn_mfma_f32_16x16x32_bf16(a1, b0, acc[1][0], 0, 0, 0);
        acc[1][1] = __builtin_amdgcn_mfma_f32_16x16x32_bf16(a1, b1, acc[1][1], 0, 0, 0);
        __syncthreads();
    }

    const int rb_ = m0 + wm + (lane >> 4) * 4;
    #pragma unroll
    for (int mi = 0; mi < 2; ++mi)
        #pragma unroll
        for (int ni = 0; ni < 2; ++ni) {
            int col = n0 + wn + ni * 16 + l15;
            if (col < N) {
                #pragma unroll
                for (int j = 0; j < 4; ++j)
                    epi(rb_ + mi * 16 + j, col, acc[mi][ni][j]);
            }
        }
}

// Epilogues ----------------------------------------------------------------
struct EpiTanh {
    unsigned short* O; int ldo;
    __device__ void operator()(int r, int c, float v) const {
        O[(size_t)r * ldo + c] = f2bf(tanhf(v));
    }
};
struct EpiF32 {
    float* O;
    __device__ void operator()(int r, int c, float v) const {
        O[(size_t)r * 768 + c] = v;
    }
};
struct EpiDec {
    const float* td; float* O;
    __device__ void operator()(int r, int c, float v) const {
        O[(size_t)r * 768 + c] = expf(-expf(td[c] + v));
    }
};
struct EpiMix {
    const float* px; const float* pxx;
    const float* maa[5];
    unsigned short* outs[5];
    __device__ void operator()(int r, int c, float v) const {
        int kk = c / 768;
        int cc = c - kk * 768;
        size_t o = (size_t)r * 768 + cc;
        outs[kk][o] = f2bf(fmaf(pxx[o], maa[kk][cc] + v, px[o]));
    }
};
struct EpiRKVG {
    unsigned short* O; bool silu;
    __device__ void operator()(int r, int c, float v) const {
        if (silu) v = v / (1.f + expf(-v));
        O[(size_t)r * 768 + c] = f2bf(v);
    }
};

template<int KDIM, class Epi>
__global__ __launch_bounds__(256) void gemm_one(const unsigned short* __restrict__ A,
                                                const unsigned short* __restrict__ W,
                                                int N, Epi epi)
{
    gemm_core<KDIM>(A, W, N, epi);
}

struct QuadArgs {
    const unsigned short* A[4];
    const unsigned short* W[4];
    unsigned short* O[4];
};
__global__ __launch_bounds__(256) void gemm_quad768(QuadArgs q)
{
    const int z = blockIdx.z;
    EpiRKVG e{q.O[z], z == 3};
    gemm_core<768>(q.A[z], q.W[z], 768, e);
}

// ---------------------------------------------------------------------------
// WKV6 chunked scan. One block (4 waves) per (b,h); 16 serial chunks of L=64.
// Within chunk: A_tau[j] = prod_{s<tau} d_s[j] (cumprod);
//   r~ = r*A_tau, k~ = k/A_{tau+1}  (bf16);
//   Q = R~ @ K~^T (64x64, MFMA), P = strict_lower(Q) + diag(sum_j r*u*k);
//   y = P @ V + R~ @ S_chunk^T     (64x32, MFMA);
//   S' = D * (S + (K~^T @ V))       (32x32, MFMA + elementwise, f32 state).
// ---------------------------------------------------------------------------
__global__ __launch_bounds__(256) void wkv_scan(
    const unsigned short* __restrict__ r, const unsigned short* __restrict__ k,
    const unsigned short* __restrict__ v, const float* __restrict__ dec,
    const float* __restrict__ u, float* __restrict__ y)
{
    __shared__ __align__(16) unsigned short rwL[64][40], kwL[64][40];
    __shared__ __align__(16) unsigned short vT0[32][40], vT1[32][40];
    __shared__ __align__(16) unsigned short rsL[64][40], ksL[64][40];
    __shared__ __align__(16) unsigned short ksT0[32][40], ksT1[32][40];
    __shared__ __align__(16) unsigned short PL0[64][40], PL1[64][40];
    __shared__ __align__(16) unsigned short STb[32][40];
    __shared__ float ST[32][32];       // state transposed: ST[i][j] = s[j][i]
    __shared__ float AL[65][32];       // cumulative decay products
    __shared__ float segprod[8][32];
    __shared__ float dpart[64][4];
    __shared__ float diagL[64];
    __shared__ float uL[32];

    const int bh = blockIdx.x;
    const int b = bh / NH_, h = bh % NH_;
    const int tid  = threadIdx.x;
    const int lane = tid & 63;
    const int wv   = tid >> 6;
    const int l15  = lane & 15;
    const int kb8  = (lane >> 4) * 8;
    const int rb4  = (lane >> 4) * 4;

    const size_t base0 = ((size_t)b * TT) * CC + (size_t)h * HS_;

    if (tid < 32) uL[tid] = u[h * HS_ + tid];
    for (int q = tid; q < 1024; q += 256) {
        ST[q >> 5][q & 31]  = 0.f;
        STb[q >> 5][q & 31] = 0;
    }
    __syncthreads();

    const int lrow = tid >> 2, lq = (tid & 3) * 8;   // loader: tau, col-octet
    const int cj = tid & 31, cseg = tid >> 5;        // cumprod: channel, tau-segment

    for (int tc = 0; tc < TT; tc += 64) {
        // ---- phase a: load r,k,v chunk into LDS (v transposed) ----
        {
            size_t gp = base0 + (size_t)(tc + lrow) * CC + lq;
            uint4 rv = *(const uint4*)(r + gp);
            uint4 kv = *(const uint4*)(k + gp);
            uint4 vv = *(const uint4*)(v + gp);
            *(uint4*)&rwL[lrow][lq] = rv;
            *(uint4*)&kwL[lrow][lq] = kv;
            const unsigned short* vp = (const unsigned short*)&vv;
            if (lrow < 32) {
                #pragma unroll
                for (int e = 0; e < 8; ++e) vT0[lq + e][lrow] = vp[e];
            } else {
                #pragma unroll
                for (int e = 0; e < 8; ++e) vT1[lq + e][lrow - 32] = vp[e];
            }
        }
        // ---- decay loads + per-segment product ----
        float dv[8];
        #pragma unroll
        for (int q = 0; q < 8; ++q)
            dv[q] = dec[base0 + (size_t)(tc + cseg * 8 + q) * CC + cj];
        {
            float lp = dv[0];
            #pragma unroll
            for (int q = 1; q < 8; ++q) lp *= dv[q];
            segprod[cseg][cj] = lp;
        }
        __syncthreads();  // rwL,kwL,vT,segprod visible

        // ---- diag partials: sum_j r*u*k ----
        {
            const int ptau = tid >> 2, pp = tid & 3;
            float acc = 0.f;
            #pragma unroll
            for (int e = 0; e < 8; ++e) {
                int j = pp * 8 + e;
                acc += bf2f(rwL[ptau][j]) * uL[j] * bf2f(kwL[ptau][j]);
            }
            dpart[ptau][pp] = acc;
        }
        // ---- cumprod fill: AL[tau][j], AL[64][j] = full chunk decay ----
        {
            float pre = 1.f;
            #pragma unroll
            for (int s = 0; s < 7; ++s) if (s < cseg) pre *= segprod[s][cj];
            float run = pre;
            #pragma unroll
            for (int q = 0; q < 8; ++q) {
                AL[cseg * 8 + q][cj] = run;
                run *= dv[q];
            }
            if (cseg == 7) AL[64][cj] = run;
        }
        __syncthreads();  // AL, dpart visible

        if (tid < 64)
            diagL[tid] = dpart[tid][0] + dpart[tid][1] + dpart[tid][2] + dpart[tid][3];

        // ---- scale: r~ = r*A_tau, k~ = k/A_{tau+1} ----
        #pragma unroll
        for (int q = 0; q < 8; ++q) {
            int tau = cseg * 8 + q;
            float a  = AL[tau][cj];
            float ia = 1.f / AL[tau + 1][cj];
            unsigned short rs = f2bf(bf2f(rwL[tau][cj]) * a);
            unsigned short ks = f2bf(bf2f(kwL[tau][cj]) * ia);
            rsL[tau][cj] = rs;
            ksL[tau][cj] = ks;
            if (tau < 32) ksT0[cj][tau] = ks; else ksT1[cj][tau - 32] = ks;
        }
        __syncthreads();  // rsL,ksL,ksT,diagL visible

        // ---- phase d: Q = R~ @ K~^T (wave quadrant 32x32), mask -> PL ----
        {
            const int wm = (wv >> 1) * 32, wn = (wv & 1) * 32;
            bf16x8 a0 = *(const bf16x8*)&rsL[wm + l15][kb8];
            bf16x8 a1 = *(const bf16x8*)&rsL[wm + 16 + l15][kb8];
            bf16x8 b0 = *(const bf16x8*)&ksL[wn + l15][kb8];
            bf16x8 b1 = *(const bf16x8*)&ksL[wn + 16 + l15][kb8];
            f32x4 qf[2][2];
            #pragma unroll
            for (int mi = 0; mi < 2; ++mi)
                #pragma unroll
                for (int ni = 0; ni < 2; ++ni)
                    #pragma unroll
                    for (int e = 0; e < 4; ++e) qf[mi][ni][e] = 0.f;
            qf[0][0] = __builtin_amdgcn_mfma_f32_16x16x32_bf16(a0, b0, qf[0][0], 0, 0, 0);
            qf[0][1] = __builtin_amdgcn_mfma_f32_16x16x32_bf16(a0, b1, qf[0][1], 0, 0, 0);
            qf[1][0] = __builtin_amdgcn_mfma_f32_16x16x32_bf16(a1, b0, qf[1][0], 0, 0, 0);
            qf[1][1] = __builtin_amdgcn_mfma_f32_16x16x32_bf16(a1, b1, qf[1][1], 0, 0, 0);
            #pragma unroll
            for (int mi = 0; mi < 2; ++mi)
                #pragma unroll
                for (int ni = 0; ni < 2; ++ni) {
                    const int col = wn + ni * 16 + l15;
                    #pragma unroll
                    for (int jj = 0; jj < 4; ++jj) {
                        const int row = wm + mi * 16 + rb4 + jj;
                        float val = (col < row) ? qf[mi][ni][jj]
                                  : ((col == row) ? diagL[row] : 0.f);
                        unsigned short bvv = f2bf(val);
                        if (col < 32) PL0[row][col] = bvv;
                        else          PL1[row][col - 32] = bvv;
                    }
                }
        }
        __syncthreads();  // PL visible

        // ---- phase e: y = P @ V + R~ @ S^T  (wave rows [16w,16w+16)) ----
        {
            const int mr = wv * 16;
            bf16x8 pa0 = *(const bf16x8*)&PL0[mr + l15][kb8];
            bf16x8 pa1 = *(const bf16x8*)&PL1[mr + l15][kb8];
            bf16x8 ra  = *(const bf16x8*)&rsL[mr + l15][kb8];
            #pragma unroll
            for (int ni = 0; ni < 2; ++ni) {
                bf16x8 bv0 = *(const bf16x8*)&vT0[ni * 16 + l15][kb8];
                bf16x8 bv1 = *(const bf16x8*)&vT1[ni * 16 + l15][kb8];
                bf16x8 bs  = *(const bf16x8*)&STb[ni * 16 + l15][kb8];
                f32x4 acc;
                #pragma unroll
                for (int e = 0; e < 4; ++e) acc[e] = 0.f;
                acc = __builtin_amdgcn_mfma_f32_16x16x32_bf16(pa0, bv0, acc, 0, 0, 0);
                acc = __builtin_amdgcn_mfma_f32_16x16x32_bf16(pa1, bv1, acc, 0, 0, 0);
                acc = __builtin_amdgcn_mfma_f32_16x16x32_bf16(ra,  bs,  acc, 0, 0, 0);
                #pragma unroll
                for (int jj = 0; jj < 4; ++jj)
                    y[base0 + (size_t)(tc + mr + rb4 + jj) * CC + ni * 16 + l15] = acc[jj];
            }
        }
        __syncthreads();  // all STb readers done

        // ---- phase f: KVT = V^T @ K~ (32x32), state update ----
        {
            const int mi = (wv >> 1) * 16, nj = (wv & 1) * 16;
            bf16x8 av0 = *(const bf16x8*)&vT0[mi + l15][kb8];
            bf16x8 av1 = *(const bf16x8*)&vT1[mi + l15][kb8];
            bf16x8 bk0 = *(const bf16x8*)&ksT0[nj + l15][kb8];
            bf16x8 bk1 = *(const bf16x8*)&ksT1[nj + l15][kb8];
            f32x4 acc;
            #pragma unroll
            for (int e = 0; e < 4; ++e) acc[e] = 0.f;
            acc = __builtin_amdgcn_mfma_f32_16x16x32_bf16(av0, bk0, acc, 0, 0, 0);
            acc = __builtin_amdgcn_mfma_f32_16x16x32_bf16(av1, bk1, acc, 0, 0, 0);
            const int j = nj + l15;
            const float D = AL[64][j];
            #pragma unroll
            for (int jj = 0; jj < 4; ++jj) {
                const int i = mi + rb4 + jj;
                float ns = D * (ST[i][j] + acc[jj]);
                ST[i][j]  = ns;
                STb[i][j] = f2bf(ns);
            }
        }
        __syncthreads();  // STb updated; guards next-chunk LDS overwrite
    }
}

// ---------------------------------------------------------------------------
// LayerNorm(y) * g -> bf16 z
// ---------------------------------------------------------------------------
__global__ __launch_bounds__(256) void ln_gate(
    const float* __restrict__ y, const unsigned short* __restrict__ g,
    const float* __restrict__ lnw, const float* __restrict__ lnb,
    unsigned short* __restrict__ z)
{
    __shared__ float sy[CC];
    __shared__ float rbuf[8];
    __shared__ float stats[2];

    const int row = blockIdx.x, tid = threadIdx.x;
    const float* yr = y + (size_t)row * CC;

    float s1 = 0.f, s2 = 0.f;
    #pragma unroll
    for (int q = 0; q < 3; ++q) {
        int c = tid + q * 256;
        float vv = yr[c];
        sy[c] = vv;
        s1 += vv;
        s2 += vv * vv;
    }
    #pragma unroll
    for (int off = 32; off > 0; off >>= 1) {
        s1 += __shfl_down(s1, off);
        s2 += __shfl_down(s2, off);
    }
    const int wid = tid >> 6;
    if ((tid & 63) == 0) { rbuf[wid] = s1; rbuf[4 + wid] = s2; }
    __syncthreads();
    if (tid == 0) {
        float S1 = rbuf[0] + rbuf[1] + rbuf[2] + rbuf[3];
        float S2 = rbuf[4] + rbuf[5] + rbuf[6] + rbuf[7];
        float mu = S1 / (float)CC;
        float var = S2 / (float)CC - mu * mu;
        stats[0] = mu;
        stats[1] = rsqrtf(var + 1e-5f);
    }
    __syncthreads();
    const float mu = stats[0], rstd = stats[1];
    const unsigned short* gr = g + (size_t)row * CC;
    unsigned short* zr = z + (size_t)row * CC;
    #pragma unroll
    for (int q = 0; q < 3; ++q) {
        int c = tid + q * 256;
        zr[c] = f2bf(fmaf((sy[c] - mu) * rstd, lnw[c], lnb[c]) * bf2f(gr[c]));
    }
}

// ---------------------------------------------------------------------------
extern "C" void kernel_launch(void* const* d_in, const int* in_sizes, int n_in,
                              void* d_out, int out_size, void* d_ws, size_t ws_size,
                              hipStream_t stream)
{
    const float* x      = (const float*)d_in[0];
    const float* maa_x  = (const float*)d_in[1];
    const float* maa_w  = (const float*)d_in[2];
    const float* maa_k  = (const float*)d_in[3];
    const float* maa_v  = (const float*)d_in[4];
    const float* maa_r  = (const float*)d_in[5];
    const float* maa_g  = (const float*)d_in[6];
    const float* w1     = (const float*)d_in[7];
    const float* w2     = (const float*)d_in[8];
    const float* tdec   = (const float*)d_in[9];
    const float* tdw1   = (const float*)d_in[10];
    const float* tdw2   = (const float*)d_in[11];
    const float* faaaa  = (const float*)d_in[12];
    const float* Wr     = (const float*)d_in[13];
    const float* Wk     = (const float*)d_in[14];
    const float* Wv     = (const float*)d_in[15];
    const float* Wg     = (const float*)d_in[16];
    const float* Wo     = (const float*)d_in[17];
    const float* lnw    = (const float*)d_in[18];
    const float* lnb    = (const float*)d_in[19];

    char* base = (char*)d_ws;
    size_t off = 0;
    auto alloc = [&](size_t bytes) -> char* {
        char* p = base + off;
        off = (off + bytes + 255) & ~(size_t)255;
        return p;
    };

    float*          xx   = (float*)alloc(SZ * 4);           // later reused as y
    float*          decb = (float*)alloc(SZ * 4);
    unsigned short* xxx  = (unsigned short*)alloc(SZ * 2);  // later reused as z
    unsigned short* xw   = (unsigned short*)alloc(SZ * 2);
    unsigned short* xk   = (unsigned short*)alloc(SZ * 2);
    unsigned short* xv   = (unsigned short*)alloc(SZ * 2);
    unsigned short* xr   = (unsigned short*)alloc(SZ * 2);
    unsigned short* xg   = (unsigned short*)alloc(SZ * 2);
    unsigned short* rb   = (unsigned short*)alloc(SZ * 2);
    unsigned short* kb   = (unsigned short*)alloc(SZ * 2);
    unsigned short* vb   = (unsigned short*)alloc(SZ * 2);
    unsigned short* gb   = (unsigned short*)alloc(SZ * 2);
    unsigned short* t5   = (unsigned short*)alloc((size_t)4096 * 160 * 2);
    unsigned short* d1   = (unsigned short*)alloc((size_t)4096 * 64 * 2);
    unsigned short* w1t  = (unsigned short*)alloc((size_t)160 * 768 * 2);
    unsigned short* w2t  = (unsigned short*)alloc((size_t)3840 * 160 * 2);
    unsigned short* wrt  = (unsigned short*)alloc((size_t)768 * 768 * 2);
    unsigned short* wkt  = (unsigned short*)alloc((size_t)768 * 768 * 2);
    unsigned short* wvt  = (unsigned short*)alloc((size_t)768 * 768 * 2);
    unsigned short* wgt  = (unsigned short*)alloc((size_t)768 * 768 * 2);
    unsigned short* wot  = (unsigned short*)alloc((size_t)768 * 768 * 2);
    unsigned short* td1t = (unsigned short*)alloc((size_t)64 * 768 * 2);
    unsigned short* td2t = (unsigned short*)alloc((size_t)768 * 64 * 2);
    float*          y    = xx;   // xx dead after mixall epilogue
    unsigned short* z    = xxx;  // xxx dead after t5 GEMM

    // 1) weight prep
    TArgs ta = {{
        { w1,   w1t,  768, 160 },
        { Wr,   wrt,  768, 768 },
        { Wk,   wkt,  768, 768 },
        { Wv,   wvt,  768, 768 },
        { Wg,   wgt,  768, 768 },
        { Wo,   wot,  768, 768 },
        { tdw1, td1t, 768, 64  },
        { tdw2, td2t, 64,  768 },
    }};
    transpose_cast<<<dim3(24, 24, 8), 256, 0, stream>>>(ta);
    w2fill<<<3840, 192, 0, stream>>>(w2, w2t);

    // 2) shift + xxx
    shift_kernel<<<BB * TT, 256, 0, stream>>>(x, maa_x, xx, xxx);

    // 3) t5 = tanh(xxx @ w1)           (M=4096, K=768, N=160)
    gemm_one<768, EpiTanh><<<dim3(3, 64), 256, 0, stream>>>(xxx, w1t, 160, EpiTanh{t5, 160});

    // 4) mixall: t5 @ blockdiag(w2)    (K=160, N=3840) + demux epilogue
    EpiMix em{ x, xx,
               { maa_w, maa_k, maa_v, maa_r, maa_g },
               { xw, xk, xv, xr, xg } };
    gemm_one<160, EpiMix><<<dim3(60, 64), 256, 0, stream>>>(t5, w2t, 3840, em);

    // 5) d1 = tanh(xw @ tdw1)          (K=768, N=64)
    gemm_one<768, EpiTanh><<<dim3(1, 64), 256, 0, stream>>>(xw, td1t, 64, EpiTanh{d1, 64});

    // 6) dec = exp(-exp(tdecay + d1 @ tdw2))   (K=64, N=768)
    gemm_one<64, EpiDec><<<dim3(12, 64), 256, 0, stream>>>(d1, td2t, 768, EpiDec{tdec, decb});

    // 7) r,k,v,g GEMMs (bf16 out, silu on g)
    QuadArgs qa = {{ xr, xk, xv, xg }, { wrt, wkt, wvt, wgt }, { rb, kb, vb, gb }};
    gemm_quad768<<<dim3(12, 64, 4), 256, 0, stream>>>(qa);

    // 8) WKV chunked scan (f32 state, f32 dec)
    wkv_scan<<<BB * NH_, 256, 0, stream>>>(rb, kb, vb, decb, faaaa, y);

    // 9) LayerNorm * gate -> z (bf16)
    ln_gate<<<BB * TT, 256, 0, stream>>>(y, gb, lnw, lnb, z);

    // 10) out = z @ Wo (f32 out)
    gemm_one<768, EpiF32><<<dim3(12, 64), 256, 0, stream>>>(z, wot, 768, EpiF32{(float*)d_out});
}

// Round 5
// 302.709 us; speedup vs baseline: 3.6853x; 1.0627x over previous
//
#include <hip/hip_runtime.h>
#include <math.h>

#define BB   4
#define TT   1024
#define CC   768
#define NH_  24
#define HS_  32
#define NBH  (BB * NH_)   // 96 (b,h) pairs
#define NCH  16           // chunks
#define CL   64           // chunk length

static constexpr size_t SZ = (size_t)BB * TT * CC; // 3,145,728 elements

typedef __attribute__((ext_vector_type(8))) __bf16 bf16x8;
typedef __attribute__((ext_vector_type(4))) float  f32x4;

__device__ __forceinline__ unsigned short f2bf(float f) {
    unsigned u = __float_as_uint(f);
    unsigned r = (u + 0x7FFFu + ((u >> 16) & 1u)) >> 16;
    return (unsigned short)r;
}
__device__ __forceinline__ float bf2f(unsigned short h) {
    return __uint_as_float(((unsigned)h) << 16);
}

// ---------------------------------------------------------------------------
// Weight prep: transpose + f32->bf16 cast. dst is (C x R) row-major = N x K.
// ---------------------------------------------------------------------------
struct TDesc { const float* src; unsigned short* dst; int R, C; };
struct TArgs { TDesc d[8]; };

__global__ __launch_bounds__(256) void transpose_cast(TArgs a)
{
    __shared__ float tile[32][33];
    TDesc t = a.d[blockIdx.z];
    const int tx0 = blockIdx.x * 32, ty0 = blockIdx.y * 32;
    if (tx0 >= t.C || ty0 >= t.R) return;
    const int tx = threadIdx.x & 31, ty = threadIdx.x >> 5;
    #pragma unroll
    for (int dy = 0; dy < 4; ++dy) {
        int rr = ty0 + ty + dy * 8, cc = tx0 + tx;
        tile[ty + dy * 8][tx] = (rr < t.R && cc < t.C) ? t.src[(size_t)rr * t.C + cc] : 0.f;
    }
    __syncthreads();
    #pragma unroll
    for (int dy = 0; dy < 4; ++dy) {
        int cc = tx0 + ty + dy * 8, rr = ty0 + tx;
        if (cc < t.C && rr < t.R)
            t.dst[(size_t)cc * t.R + rr] = f2bf(tile[tx][ty + dy * 8]);
    }
}

// Build block-diagonal W2^T: (3840 x 160) bf16.
__global__ __launch_bounds__(192) void w2fill(const float* __restrict__ w2,
                                              unsigned short* __restrict__ W2t)
{
    const int n = blockIdx.x;
    const int e = threadIdx.x;
    if (e >= 160) return;
    const int kk = n / 768;
    const int c  = n - kk * 768;
    unsigned short val = 0;
    if ((e >> 5) == kk) val = f2bf(w2[(size_t)e * 768 + c]);
    W2t[(size_t)n * 160 + e] = val;
}

// ---------------------------------------------------------------------------
// shift: xx = qshift(x)-x (f32), xxx = bf16(x + xx*maa_x)
// ---------------------------------------------------------------------------
__global__ __launch_bounds__(256) void shift_kernel(
    const float* __restrict__ x, const float* __restrict__ maa_x,
    float* __restrict__ xxO, unsigned short* __restrict__ xxxO)
{
    const int tok = blockIdx.x;
    const int t   = tok & (TT - 1);
    const int hh  = t >> 5;
    const int wp  = t & 31;
    const int tid = threadIdx.x;
    const float* xrow = x + (size_t)tok * CC;
    for (int c = tid; c < CC; c += 256) {
        float xc = xrow[c];
        float sh;
        if (c < 192)      sh = (wp > 0)  ? xrow[c - CC]      : 0.f;
        else if (c < 384) sh = (wp < 31) ? xrow[c + CC]      : 0.f;
        else if (c < 576) sh = (hh > 0)  ? xrow[c - 32 * CC] : 0.f;
        else              sh = (hh < 31) ? xrow[c + 32 * CC] : 0.f;
        float xxv = sh - xc;
        size_t o = (size_t)tok * CC + c;
        xxO[o]  = xxv;
        xxxO[o] = f2bf(fmaf(xxv, maa_x[c], xc));
    }
}

// ---------------------------------------------------------------------------
// bf16 MFMA GEMM, 64x64 tile (for small-N GEMMs).
// ---------------------------------------------------------------------------
template<int KDIM, class Epi>
__device__ __forceinline__ void gemm_core(const unsigned short* __restrict__ A,
                                          const unsigned short* __restrict__ W,
                                          int N, const Epi& epi)
{
    __shared__ __align__(16) unsigned short As[64][40];
    __shared__ __align__(16) unsigned short Bs[64][40];

    const int tid  = threadIdx.x;
    const int lane = tid & 63;
    const int wv   = tid >> 6;
    const int wm   = (wv >> 1) * 32, wn = (wv & 1) * 32;
    const int m0   = blockIdx.y * 64, n0 = blockIdx.x * 64;
    const int srow = tid >> 2, scb = (tid & 3) * 8;
    const int l15  = lane & 15, kb8 = (lane >> 4) * 8;

    f32x4 acc[2][2];
    #pragma unroll
    for (int a = 0; a < 2; ++a)
        #pragma unroll
        for (int b = 0; b < 2; ++b)
            #pragma unroll
            for (int e = 0; e < 4; ++e) acc[a][b][e] = 0.f;

    const unsigned short* aP = A + (size_t)(m0 + srow) * KDIM + scb;
    const unsigned short* bP = W + (size_t)(n0 + srow) * KDIM + scb;
    const bool bvalid = (n0 + srow) < N;

    for (int k0 = 0; k0 < KDIM; k0 += 32) {
        uint4 av = *(const uint4*)(aP + k0);
        uint4 bw = make_uint4(0u, 0u, 0u, 0u);
        if (bvalid) bw = *(const uint4*)(bP + k0);
        *(uint4*)&As[srow][scb] = av;
        *(uint4*)&Bs[srow][scb] = bw;
        __syncthreads();

        bf16x8 a0 = *(const bf16x8*)&As[wm + l15][kb8];
        bf16x8 a1 = *(const bf16x8*)&As[wm + 16 + l15][kb8];
        bf16x8 b0 = *(const bf16x8*)&Bs[wn + l15][kb8];
        bf16x8 b1 = *(const bf16x8*)&Bs[wn + 16 + l15][kb8];
        acc[0][0] = __builtin_amdgcn_mfma_f32_16x16x32_bf16(a0, b0, acc[0][0], 0, 0, 0);
        acc[0][1] = __builtin_amdgcn_mfma_f32_16x16x32_bf16(a0, b1, acc[0][1], 0, 0, 0);
        acc[1][0] = __builtin_amdgcn_mfma_f32_16x16x32_bf16(a1, b0, acc[1][0], 0, 0, 0);
        acc[1][1] = __builtin_amdgcn_mfma_f32_16x16x32_bf16(a1, b1, acc[1][1], 0, 0, 0);
        __syncthreads();
    }

    const int rb_ = m0 + wm + (lane >> 4) * 4;
    #pragma unroll
    for (int mi = 0; mi < 2; ++mi)
        #pragma unroll
        for (int ni = 0; ni < 2; ++ni) {
            int col = n0 + wn + ni * 16 + l15;
            if (col < N) {
                #pragma unroll
                for (int j = 0; j < 4; ++j)
                    epi(rb_ + mi * 16 + j, col, acc[mi][ni][j]);
            }
        }
}

// ---------------------------------------------------------------------------
// bf16 MFMA GEMM, 128x128 tile, 4 waves (each 64x64 = 4x4 frags), BK=32.
// 16 MFMA per wave per K-step (4x better MFMA:barrier ratio than 64-tile).
// ---------------------------------------------------------------------------
template<int KDIM, class Epi>
__device__ __forceinline__ void gemm_core128(const unsigned short* __restrict__ A,
                                             const unsigned short* __restrict__ W,
                                             int N, const Epi& epi)
{
    __shared__ __align__(16) unsigned short As[128][40];
    __shared__ __align__(16) unsigned short Bs[128][40];

    const int tid  = threadIdx.x;
    const int lane = tid & 63;
    const int wv   = tid >> 6;
    const int wm   = (wv >> 1) * 64, wn = (wv & 1) * 64;
    const int m0   = blockIdx.y * 128, n0 = blockIdx.x * 128;
    const int l15  = lane & 15, kb8 = (lane >> 4) * 8, rb4 = (lane >> 4) * 4;
    const int sr   = tid >> 2, sq = (tid & 3) * 8;

    f32x4 acc[4][4];
    #pragma unroll
    for (int a = 0; a < 4; ++a)
        #pragma unroll
        for (int b = 0; b < 4; ++b)
            #pragma unroll
            for (int e = 0; e < 4; ++e) acc[a][b][e] = 0.f;

    const unsigned short* aP  = A + (size_t)(m0 + sr) * KDIM + sq;
    const unsigned short* aP2 = aP + (size_t)64 * KDIM;
    const unsigned short* bP  = W + (size_t)(n0 + sr) * KDIM + sq;
    const unsigned short* bP2 = bP + (size_t)64 * KDIM;
    const bool bv1 = (n0 + sr) < N, bv2 = (n0 + 64 + sr) < N;

    for (int k0 = 0; k0 < KDIM; k0 += 32) {
        uint4 a1 = *(const uint4*)(aP + k0);
        uint4 a2 = *(const uint4*)(aP2 + k0);
        uint4 b1 = make_uint4(0u, 0u, 0u, 0u);
        uint4 b2 = make_uint4(0u, 0u, 0u, 0u);
        if (bv1) b1 = *(const uint4*)(bP + k0);
        if (bv2) b2 = *(const uint4*)(bP2 + k0);
        *(uint4*)&As[sr][sq]      = a1;
        *(uint4*)&As[64 + sr][sq] = a2;
        *(uint4*)&Bs[sr][sq]      = b1;
        *(uint4*)&Bs[64 + sr][sq] = b2;
        __syncthreads();

        bf16x8 af[4], bfr[4];
        #pragma unroll
        for (int mi = 0; mi < 4; ++mi)
            af[mi] = *(const bf16x8*)&As[wm + mi * 16 + l15][kb8];
        #pragma unroll
        for (int ni = 0; ni < 4; ++ni)
            bfr[ni] = *(const bf16x8*)&Bs[wn + ni * 16 + l15][kb8];
        #pragma unroll
        for (int mi = 0; mi < 4; ++mi)
            #pragma unroll
            for (int ni = 0; ni < 4; ++ni)
                acc[mi][ni] = __builtin_amdgcn_mfma_f32_16x16x32_bf16(af[mi], bfr[ni], acc[mi][ni], 0, 0, 0);
        __syncthreads();
    }

    const int rbase = m0 + wm + rb4;
    #pragma unroll
    for (int mi = 0; mi < 4; ++mi)
        #pragma unroll
        for (int ni = 0; ni < 4; ++ni) {
            int col = n0 + wn + ni * 16 + l15;
            if (col < N) {
                #pragma unroll
                for (int j = 0; j < 4; ++j)
                    epi(rbase + mi * 16 + j, col, acc[mi][ni][j]);
            }
        }
}

// Epilogues ----------------------------------------------------------------
struct EpiTanh {
    unsigned short* O; int ldo;
    __device__ void operator()(int r, int c, float v) const {
        O[(size_t)r * ldo + c] = f2bf(tanhf(v));
    }
};
struct EpiF32 {
    float* O;
    __device__ void operator()(int r, int c, float v) const {
        O[(size_t)r * 768 + c] = v;
    }
};
struct EpiDec {
    const float* td; float* O;
    __device__ void operator()(int r, int c, float v) const {
        O[(size_t)r * 768 + c] = expf(-expf(td[c] + v));
    }
};
struct EpiMix {
    const float* px; const float* pxx;
    const float* maa[5];
    unsigned short* outs[5];
    __device__ void operator()(int r, int c, float v) const {
        int kk = c / 768;
        int cc = c - kk * 768;
        size_t o = (size_t)r * 768 + cc;
        outs[kk][o] = f2bf(fmaf(pxx[o], maa[kk][cc] + v, px[o]));
    }
};
struct EpiRKVG {
    unsigned short* O; bool silu;
    __device__ void operator()(int r, int c, float v) const {
        if (silu) v = v / (1.f + expf(-v));
        O[(size_t)r * 768 + c] = f2bf(v);
    }
};

template<int KDIM, class Epi>
__global__ __launch_bounds__(256) void gemm_one(const unsigned short* __restrict__ A,
                                                const unsigned short* __restrict__ W,
                                                int N, Epi epi)
{
    gemm_core<KDIM>(A, W, N, epi);
}

template<int KDIM, class Epi>
__global__ __launch_bounds__(256) void gemm_one128(const unsigned short* __restrict__ A,
                                                   const unsigned short* __restrict__ W,
                                                   int N, Epi epi)
{
    gemm_core128<KDIM>(A, W, N, epi);
}

struct QuadArgs {
    const unsigned short* A[4];
    const unsigned short* W[4];
    unsigned short* O[4];
};
__global__ __launch_bounds__(256) void gemm_quad768(QuadArgs q)
{
    const int z = blockIdx.z;
    EpiRKVG e{q.O[z], z == 3};
    gemm_core128<768>(q.A[z], q.W[z], 768, e);
}

// ---------------------------------------------------------------------------
// WKV6 parallel chunked scan, 3 phases.
// Phase 1 (wkv_local): per (chunk, bh) block. Local masked attention:
//   y_loc = (strict_lower(R~K~^T) + diag(sum r*u*k)) @ V ; emit KVT_c (f32),
//   D_c = full-chunk decay, r~ (bf16, for phase 3).
// ---------------------------------------------------------------------------
__global__ __launch_bounds__(256) void wkv_local(
    const unsigned short* __restrict__ r, const unsigned short* __restrict__ k,
    const unsigned short* __restrict__ v, const float* __restrict__ dec,
    const float* __restrict__ u, float* __restrict__ y,
    unsigned short* __restrict__ rsb, float* __restrict__ kvt,
    float* __restrict__ dcv)
{
    __shared__ __align__(16) unsigned short rwL[64][40], kwL[64][40]; // raw -> scaled in place
    __shared__ __align__(16) unsigned short vT0[32][40], vT1[32][40];
    __shared__ __align__(16) unsigned short ksT0[32][40], ksT1[32][40];
    __shared__ __align__(16) unsigned short PL0[64][40], PL1[64][40];
    __shared__ float AL[65][32];
    __shared__ float segprod[8][32];
    __shared__ float dpart[64][4];
    __shared__ float diagL[64];
    __shared__ float uL[32];

    const int c   = blockIdx.x;
    const int bh  = blockIdx.y;
    const int b = bh / NH_, h = bh % NH_;
    const int tid  = threadIdx.x;
    const int lane = tid & 63;
    const int wv   = tid >> 6;
    const int l15  = lane & 15;
    const int kb8  = (lane >> 4) * 8;
    const int rb4  = (lane >> 4) * 4;
    const int tc   = c * CL;

    const size_t base0 = ((size_t)b * TT) * CC + (size_t)h * HS_;

    if (tid < 32) uL[tid] = u[h * HS_ + tid];

    const int lrow = tid >> 2, lq = (tid & 3) * 8;
    const int cj = tid & 31, cseg = tid >> 5;

    // ---- load r,k,v (v transposed) ----
    {
        size_t gp = base0 + (size_t)(tc + lrow) * CC + lq;
        uint4 rv = *(const uint4*)(r + gp);
        uint4 kv = *(const uint4*)(k + gp);
        uint4 vv = *(const uint4*)(v + gp);
        *(uint4*)&rwL[lrow][lq] = rv;
        *(uint4*)&kwL[lrow][lq] = kv;
        const unsigned short* vp = (const unsigned short*)&vv;
        if (lrow < 32) {
            #pragma unroll
            for (int e = 0; e < 8; ++e) vT0[lq + e][lrow] = vp[e];
        } else {
            #pragma unroll
            for (int e = 0; e < 8; ++e) vT1[lq + e][lrow - 32] = vp[e];
        }
    }
    // ---- decay loads + per-segment product ----
    float dv[8];
    #pragma unroll
    for (int q = 0; q < 8; ++q)
        dv[q] = dec[base0 + (size_t)(tc + cseg * 8 + q) * CC + cj];
    {
        float lp = dv[0];
        #pragma unroll
        for (int q = 1; q < 8; ++q) lp *= dv[q];
        segprod[cseg][cj] = lp;
    }
    __syncthreads();

    // ---- diag partials: sum_j r*u*k (raw r,k) ----
    {
        const int ptau = tid >> 2, pp = tid & 3;
        float acc = 0.f;
        #pragma unroll
        for (int e = 0; e < 8; ++e) {
            int j = pp * 8 + e;
            acc += bf2f(rwL[ptau][j]) * uL[j] * bf2f(kwL[ptau][j]);
        }
        dpart[ptau][pp] = acc;
    }
    // ---- cumprod: AL[tau][j]; AL[64][j] = full-chunk decay ----
    {
        float pre = 1.f;
        #pragma unroll
        for (int s = 0; s < 7; ++s) if (s < cseg) pre *= segprod[s][cj];
        float run = pre;
        #pragma unroll
        for (int q = 0; q < 8; ++q) {
            AL[cseg * 8 + q][cj] = run;
            run *= dv[q];
        }
        if (cseg == 7) AL[64][cj] = run;
    }
    __syncthreads();

    if (tid < 64)
        diagL[tid] = dpart[tid][0] + dpart[tid][1] + dpart[tid][2] + dpart[tid][3];
    if (tid < 32)
        dcv[((size_t)bh * NCH + c) * 32 + tid] = AL[64][tid];

    // ---- scale in place: r~ = r*A_tau, k~ = k/A_{tau+1} ----
    #pragma unroll
    for (int q = 0; q < 8; ++q) {
        int tau = cseg * 8 + q;
        float a  = AL[tau][cj];
        float ia = 1.f / AL[tau + 1][cj];
        unsigned short rs = f2bf(bf2f(rwL[tau][cj]) * a);
        unsigned short ks = f2bf(bf2f(kwL[tau][cj]) * ia);
        rwL[tau][cj] = rs;
        kwL[tau][cj] = ks;
        if (tau < 32) ksT0[cj][tau] = ks; else ksT1[cj][tau - 32] = ks;
    }
    __syncthreads();

    // ---- Q = R~ @ K~^T (wave quadrant 32x32), mask -> PL ----
    {
        const int wm = (wv >> 1) * 32, wn = (wv & 1) * 32;
        bf16x8 a0 = *(const bf16x8*)&rwL[wm + l15][kb8];
        bf16x8 a1 = *(const bf16x8*)&rwL[wm + 16 + l15][kb8];
        bf16x8 b0 = *(const bf16x8*)&kwL[wn + l15][kb8];
        bf16x8 b1 = *(const bf16x8*)&kwL[wn + 16 + l15][kb8];
        f32x4 qf[2][2];
        #pragma unroll
        for (int mi = 0; mi < 2; ++mi)
            #pragma unroll
            for (int ni = 0; ni < 2; ++ni)
                #pragma unroll
                for (int e = 0; e < 4; ++e) qf[mi][ni][e] = 0.f;
        qf[0][0] = __builtin_amdgcn_mfma_f32_16x16x32_bf16(a0, b0, qf[0][0], 0, 0, 0);
        qf[0][1] = __builtin_amdgcn_mfma_f32_16x16x32_bf16(a0, b1, qf[0][1], 0, 0, 0);
        qf[1][0] = __builtin_amdgcn_mfma_f32_16x16x32_bf16(a1, b0, qf[1][0], 0, 0, 0);
        qf[1][1] = __builtin_amdgcn_mfma_f32_16x16x32_bf16(a1, b1, qf[1][1], 0, 0, 0);
        #pragma unroll
        for (int mi = 0; mi < 2; ++mi)
            #pragma unroll
            for (int ni = 0; ni < 2; ++ni) {
                const int col = wn + ni * 16 + l15;
                #pragma unroll
                for (int jj = 0; jj < 4; ++jj) {
                    const int row = wm + mi * 16 + rb4 + jj;
                    float val = (col < row) ? qf[mi][ni][jj]
                              : ((col == row) ? diagL[row] : 0.f);
                    unsigned short bvv = f2bf(val);
                    if (col < 32) PL0[row][col] = bvv;
                    else          PL1[row][col - 32] = bvv;
                }
            }
    }
    __syncthreads();

    // ---- emit r~ to global (phase-3 input) ----
    *(uint4*)(rsb + base0 + (size_t)(tc + lrow) * CC + lq) = *(const uint4*)&rwL[lrow][lq];

    // ---- y_loc = P @ V (wave rows [16w,16w+16)) ----
    {
        const int mr = wv * 16;
        bf16x8 pa0 = *(const bf16x8*)&PL0[mr + l15][kb8];
        bf16x8 pa1 = *(const bf16x8*)&PL1[mr + l15][kb8];
        #pragma unroll
        for (int ni = 0; ni < 2; ++ni) {
            bf16x8 bv0 = *(const bf16x8*)&vT0[ni * 16 + l15][kb8];
            bf16x8 bv1 = *(const bf16x8*)&vT1[ni * 16 + l15][kb8];
            f32x4 acc;
            #pragma unroll
            for (int e = 0; e < 4; ++e) acc[e] = 0.f;
            acc = __builtin_amdgcn_mfma_f32_16x16x32_bf16(pa0, bv0, acc, 0, 0, 0);
            acc = __builtin_amdgcn_mfma_f32_16x16x32_bf16(pa1, bv1, acc, 0, 0, 0);
            #pragma unroll
            for (int jj = 0; jj < 4; ++jj)
                y[base0 + (size_t)(tc + mr + rb4 + jj) * CC + ni * 16 + l15] = acc[jj];
        }
    }

    // ---- KVT_c = V^T @ K~ (32x32) -> global f32 (no barrier needed:
    //      vT/ksT stable since earlier barriers) ----
    {
        const int mi_ = (wv >> 1) * 16, nj = (wv & 1) * 16;
        bf16x8 av0 = *(const bf16x8*)&vT0[mi_ + l15][kb8];
        bf16x8 av1 = *(const bf16x8*)&vT1[mi_ + l15][kb8];
        bf16x8 bk0 = *(const bf16x8*)&ksT0[nj + l15][kb8];
        bf16x8 bk1 = *(const bf16x8*)&ksT1[nj + l15][kb8];
        f32x4 acc;
        #pragma unroll
        for (int e = 0; e < 4; ++e) acc[e] = 0.f;
        acc = __builtin_amdgcn_mfma_f32_16x16x32_bf16(av0, bk0, acc, 0, 0, 0);
        acc = __builtin_amdgcn_mfma_f32_16x16x32_bf16(av1, bk1, acc, 0, 0, 0);
        const int j = nj + l15;
        const size_t sb = ((size_t)bh * NCH + c) << 10;
        #pragma unroll
        for (int jj = 0; jj < 4; ++jj)
            kvt[sb + (size_t)(mi_ + rb4 + jj) * 32 + j] = acc[jj];
    }
}

// ---------------------------------------------------------------------------
// Phase 2: serial scan over 16 chunks. S = D_c*(S + KVT_c); store S (bf16)
// as the PREVIOUS state for chunk c+1. 96 blocks x 256 threads x 4 elems.
// ---------------------------------------------------------------------------
__global__ __launch_bounds__(256) void wkv_carry(
    const float* __restrict__ kvt, const float* __restrict__ dcv,
    unsigned short* __restrict__ spv)
{
    const int bh = blockIdx.x;
    const int tid = threadIdx.x;
    const int e0 = tid << 2;
    const int j0 = e0 & 31;
    float s0 = 0.f, s1 = 0.f, s2 = 0.f, s3 = 0.f;
    #pragma unroll
    for (int c = 0; c < NCH; ++c) {
        const size_t sb = (size_t)bh * NCH + c;
        float4 kv = *(const float4*)(kvt + (sb << 10) + e0);
        float4 d4 = *(const float4*)(dcv + sb * 32 + j0);
        s0 = d4.x * (s0 + kv.x);
        s1 = d4.y * (s1 + kv.y);
        s2 = d4.z * (s2 + kv.z);
        s3 = d4.w * (s3 + kv.w);
        if (c < NCH - 1) {
            unsigned lo = (unsigned)f2bf(s0) | ((unsigned)f2bf(s1) << 16);
            unsigned hi = (unsigned)f2bf(s2) | ((unsigned)f2bf(s3) << 16);
            *(uint2*)(spv + ((sb + 1) << 10) + e0) = make_uint2(lo, hi);
        }
    }
}

// ---------------------------------------------------------------------------
// Phase 3: y += R~ @ Sprev^T per chunk (chunks 1..15; chunk 0 has S=0).
// ---------------------------------------------------------------------------
__global__ __launch_bounds__(256) void wkv_stadd(
    const unsigned short* __restrict__ rsb, const unsigned short* __restrict__ spv,
    float* __restrict__ y)
{
    __shared__ __align__(16) unsigned short rsL[64][40];
    __shared__ __align__(16) unsigned short STb[32][40];

    const int c  = blockIdx.x + 1;
    const int bh = blockIdx.y;
    const int b = bh / NH_, h = bh % NH_;
    const int tid = threadIdx.x, lane = tid & 63, wv = tid >> 6;
    const int l15 = lane & 15, kb8 = (lane >> 4) * 8, rb4 = (lane >> 4) * 4;
    const int tc = c * CL;
    const size_t base0 = ((size_t)b * TT) * CC + (size_t)h * HS_;
    const int lrow = tid >> 2, lq = (tid & 3) * 8;

    *(uint4*)&rsL[lrow][lq] = *(const uint4*)(rsb + base0 + (size_t)(tc + lrow) * CC + lq);
    if (tid < 128) {
        int row = tid >> 2, q = (tid & 3) * 8;
        *(uint4*)&STb[row][q] =
            *(const uint4*)(spv + (((size_t)bh * NCH + c) << 10) + (size_t)row * 32 + q);
    }
    __syncthreads();

    const int mr = wv * 16;
    bf16x8 ra = *(const bf16x8*)&rsL[mr + l15][kb8];
    #pragma unroll
    for (int ni = 0; ni < 2; ++ni) {
        bf16x8 bs = *(const bf16x8*)&STb[ni * 16 + l15][kb8];
        f32x4 acc;
        #pragma unroll
        for (int e = 0; e < 4; ++e) acc[e] = 0.f;
        acc = __builtin_amdgcn_mfma_f32_16x16x32_bf16(ra, bs, acc, 0, 0, 0);
        #pragma unroll
        for (int jj = 0; jj < 4; ++jj) {
            size_t gp = base0 + (size_t)(tc + mr + rb4 + jj) * CC + ni * 16 + l15;
            y[gp] += acc[jj];
        }
    }
}

// ---------------------------------------------------------------------------
// LayerNorm(y) * g -> bf16 z
// ---------------------------------------------------------------------------
__global__ __launch_bounds__(256) void ln_gate(
    const float* __restrict__ y, const unsigned short* __restrict__ g,
    const float* __restrict__ lnw, const float* __restrict__ lnb,
    unsigned short* __restrict__ z)
{
    __shared__ float sy[CC];
    __shared__ float rbuf[8];
    __shared__ float stats[2];

    const int row = blockIdx.x, tid = threadIdx.x;
    const float* yr = y + (size_t)row * CC;

    float s1 = 0.f, s2 = 0.f;
    #pragma unroll
    for (int q = 0; q < 3; ++q) {
        int c = tid + q * 256;
        float vv = yr[c];
        sy[c] = vv;
        s1 += vv;
        s2 += vv * vv;
    }
    #pragma unroll
    for (int off = 32; off > 0; off >>= 1) {
        s1 += __shfl_down(s1, off);
        s2 += __shfl_down(s2, off);
    }
    const int wid = tid >> 6;
    if ((tid & 63) == 0) { rbuf[wid] = s1; rbuf[4 + wid] = s2; }
    __syncthreads();
    if (tid == 0) {
        float S1 = rbuf[0] + rbuf[1] + rbuf[2] + rbuf[3];
        float S2 = rbuf[4] + rbuf[5] + rbuf[6] + rbuf[7];
        float mu = S1 / (float)CC;
        float var = S2 / (float)CC - mu * mu;
        stats[0] = mu;
        stats[1] = rsqrtf(var + 1e-5f);
    }
    __syncthreads();
    const float mu = stats[0], rstd = stats[1];
    const unsigned short* gr = g + (size_t)row * CC;
    unsigned short* zr = z + (size_t)row * CC;
    #pragma unroll
    for (int q = 0; q < 3; ++q) {
        int c = tid + q * 256;
        zr[c] = f2bf(fmaf((sy[c] - mu) * rstd, lnw[c], lnb[c]) * bf2f(gr[c]));
    }
}

// ---------------------------------------------------------------------------
extern "C" void kernel_launch(void* const* d_in, const int* in_sizes, int n_in,
                              void* d_out, int out_size, void* d_ws, size_t ws_size,
                              hipStream_t stream)
{
    const float* x      = (const float*)d_in[0];
    const float* maa_x  = (const float*)d_in[1];
    const float* maa_w  = (const float*)d_in[2];
    const float* maa_k  = (const float*)d_in[3];
    const float* maa_v  = (const float*)d_in[4];
    const float* maa_r  = (const float*)d_in[5];
    const float* maa_g  = (const float*)d_in[6];
    const float* w1     = (const float*)d_in[7];
    const float* w2     = (const float*)d_in[8];
    const float* tdec   = (const float*)d_in[9];
    const float* tdw1   = (const float*)d_in[10];
    const float* tdw2   = (const float*)d_in[11];
    const float* faaaa  = (const float*)d_in[12];
    const float* Wr     = (const float*)d_in[13];
    const float* Wk     = (const float*)d_in[14];
    const float* Wv     = (const float*)d_in[15];
    const float* Wg     = (const float*)d_in[16];
    const float* Wo     = (const float*)d_in[17];
    const float* lnw    = (const float*)d_in[18];
    const float* lnb    = (const float*)d_in[19];

    char* base = (char*)d_ws;
    size_t off = 0;
    auto alloc = [&](size_t bytes) -> char* {
        char* p = base + off;
        off = (off + bytes + 255) & ~(size_t)255;
        return p;
    };

    float*          xx   = (float*)alloc(SZ * 4);           // later reused as y
    float*          decb = (float*)alloc(SZ * 4);
    unsigned short* xxx  = (unsigned short*)alloc(SZ * 2);  // later reused as z
    unsigned short* xw   = (unsigned short*)alloc(SZ * 2);
    unsigned short* xk   = (unsigned short*)alloc(SZ * 2);  // later reused as kvtb
    unsigned short* xv   = (unsigned short*)alloc(SZ * 2);  // later reused as spvb
    unsigned short* xr   = (unsigned short*)alloc(SZ * 2);  // later reused as rsb
    unsigned short* xg   = (unsigned short*)alloc(SZ * 2);  // later reused as dcb
    unsigned short* rb   = (unsigned short*)alloc(SZ * 2);
    unsigned short* kb   = (unsigned short*)alloc(SZ * 2);
    unsigned short* vb   = (unsigned short*)alloc(SZ * 2);
    unsigned short* gb   = (unsigned short*)alloc(SZ * 2);
    unsigned short* t5   = (unsigned short*)alloc((size_t)4096 * 160 * 2);
    unsigned short* d1   = (unsigned short*)alloc((size_t)4096 * 64 * 2);
    unsigned short* w1t  = (unsigned short*)alloc((size_t)160 * 768 * 2);
    unsigned short* w2t  = (unsigned short*)alloc((size_t)3840 * 160 * 2);
    unsigned short* wrt  = (unsigned short*)alloc((size_t)768 * 768 * 2);
    unsigned short* wkt  = (unsigned short*)alloc((size_t)768 * 768 * 2);
    unsigned short* wvt  = (unsigned short*)alloc((size_t)768 * 768 * 2);
    unsigned short* wgt  = (unsigned short*)alloc((size_t)768 * 768 * 2);
    unsigned short* wot  = (unsigned short*)alloc((size_t)768 * 768 * 2);
    unsigned short* td1t = (unsigned short*)alloc((size_t)64 * 768 * 2);
    unsigned short* td2t = (unsigned short*)alloc((size_t)768 * 64 * 2);

    float*          y    = xx;                      // xx dead after mixall
    unsigned short* z    = xxx;                     // xxx dead after t5 GEMM
    // wkv scratch aliases (xk/xv/xr/xg dead after gemm_quad768):
    unsigned short* rsb  = xr;                      // SZ bf16
    float*          kvtb = (float*)xk;              // 96*16*1024 f32 = 6.29MB <= SZ*2
    unsigned short* spvb = xv;                      // 96*16*1024 bf16 = 3.15MB
    float*          dcb  = (float*)xg;              // 96*16*32 f32 = 197KB

    // 1) weight prep
    TArgs ta = {{
        { w1,   w1t,  768, 160 },
        { Wr,   wrt,  768, 768 },
        { Wk,   wkt,  768, 768 },
        { Wv,   wvt,  768, 768 },
        { Wg,   wgt,  768, 768 },
        { Wo,   wot,  768, 768 },
        { tdw1, td1t, 768, 64  },
        { tdw2, td2t, 64,  768 },
    }};
    transpose_cast<<<dim3(24, 24, 8), 256, 0, stream>>>(ta);
    w2fill<<<3840, 192, 0, stream>>>(w2, w2t);

    // 2) shift + xxx
    shift_kernel<<<BB * TT, 256, 0, stream>>>(x, maa_x, xx, xxx);

    // 3) t5 = tanh(xxx @ w1)           (M=4096, K=768, N=160) 64-tile
    gemm_one<768, EpiTanh><<<dim3(3, 64), 256, 0, stream>>>(xxx, w1t, 160, EpiTanh{t5, 160});

    // 4) mixall: t5 @ blockdiag(w2)    (K=160, N=3840) 128-tile + demux
    EpiMix em{ x, xx,
               { maa_w, maa_k, maa_v, maa_r, maa_g },
               { xw, xk, xv, xr, xg } };
    gemm_one128<160, EpiMix><<<dim3(30, 32), 256, 0, stream>>>(t5, w2t, 3840, em);

    // 5) d1 = tanh(xw @ tdw1)          (K=768, N=64) 64-tile
    gemm_one<768, EpiTanh><<<dim3(1, 64), 256, 0, stream>>>(xw, td1t, 64, EpiTanh{d1, 64});

    // 6) dec = exp(-exp(tdecay + d1 @ tdw2))   (K=64, N=768) 64-tile
    gemm_one<64, EpiDec><<<dim3(12, 64), 256, 0, stream>>>(d1, td2t, 768, EpiDec{tdec, decb});

    // 7) r,k,v,g GEMMs (128-tile, silu on g)
    QuadArgs qa = {{ xr, xk, xv, xg }, { wrt, wkt, wvt, wgt }, { rb, kb, vb, gb }};
    gemm_quad768<<<dim3(6, 32, 4), 256, 0, stream>>>(qa);

    // 8) WKV parallel chunked scan
    wkv_local<<<dim3(NCH, NBH), 256, 0, stream>>>(rb, kb, vb, decb, faaaa, y, rsb, kvtb, dcb);
    wkv_carry<<<NBH, 256, 0, stream>>>(kvtb, dcb, spvb);
    wkv_stadd<<<dim3(NCH - 1, NBH), 256, 0, stream>>>(rsb, spvb, y);

    // 9) LayerNorm * gate -> z (bf16)
    ln_gate<<<BB * TT, 256, 0, stream>>>(y, gb, lnw, lnb, z);

    // 10) out = z @ Wo (f32 out) 128-tile
    gemm_one128<768, EpiF32><<<dim3(6, 32), 256, 0, stream>>>(z, wot, 768, EpiF32{(float*)d_out});
}

// Round 6
// 267.224 us; speedup vs baseline: 4.1746x; 1.1328x over previous
//
#include <hip/hip_runtime.h>
#include <math.h>

#define BB   4
#define TT   1024
#define CC   768
#define NH_  24
#define HS_  32
#define NBH  (BB * NH_)   // 96 (b,h) pairs
#define NCH  16           // chunks
#define CL   64           // chunk length

static constexpr size_t SZ = (size_t)BB * TT * CC; // 3,145,728 elements

typedef __attribute__((ext_vector_type(8))) __bf16 bf16x8;
typedef __attribute__((ext_vector_type(4))) float  f32x4;

__device__ __forceinline__ unsigned short f2bf(float f) {
    unsigned u = __float_as_uint(f);
    unsigned r = (u + 0x7FFFu + ((u >> 16) & 1u)) >> 16;
    return (unsigned short)r;
}
__device__ __forceinline__ float bf2f(unsigned short h) {
    return __uint_as_float(((unsigned)h) << 16);
}

// async global->LDS, 16B per lane (dest must be linear: base + lane*16)
__device__ __forceinline__ void gload16(const unsigned short* g, unsigned short* l)
{
    __builtin_amdgcn_global_load_lds(
        (const __attribute__((address_space(1))) void*)(g),
        (__attribute__((address_space(3))) void*)(l),
        16, 0, 0);
}

// bijective XCD-chunk swizzle (nwg % 8 == 0): XCD i gets contiguous idx chunk
__device__ __forceinline__ int xcd_swz(int wg, int nwg)
{
    return (wg & 7) * (nwg >> 3) + (wg >> 3);
}

// ---------------------------------------------------------------------------
// Weight prep: transpose + f32->bf16 cast. dst is (C x R) row-major = N x K.
// ---------------------------------------------------------------------------
struct TDesc { const float* src; unsigned short* dst; int R, C; };
struct TArgs { TDesc d[8]; };

__global__ __launch_bounds__(256) void transpose_cast(TArgs a)
{
    __shared__ float tile[32][33];
    TDesc t = a.d[blockIdx.z];
    const int tx0 = blockIdx.x * 32, ty0 = blockIdx.y * 32;
    if (tx0 >= t.C || ty0 >= t.R) return;
    const int tx = threadIdx.x & 31, ty = threadIdx.x >> 5;
    #pragma unroll
    for (int dy = 0; dy < 4; ++dy) {
        int rr = ty0 + ty + dy * 8, cc = tx0 + tx;
        tile[ty + dy * 8][tx] = (rr < t.R && cc < t.C) ? t.src[(size_t)rr * t.C + cc] : 0.f;
    }
    __syncthreads();
    #pragma unroll
    for (int dy = 0; dy < 4; ++dy) {
        int cc = tx0 + ty + dy * 8, rr = ty0 + tx;
        if (cc < t.C && rr < t.R)
            t.dst[(size_t)cc * t.R + rr] = f2bf(tile[tx][ty + dy * 8]);
    }
}

// Build block-diagonal W2^T: (3840 x 160) bf16.
__global__ __launch_bounds__(192) void w2fill(const float* __restrict__ w2,
                                              unsigned short* __restrict__ W2t)
{
    const int n = blockIdx.x;
    const int e = threadIdx.x;
    if (e >= 160) return;
    const int kk = n / 768;
    const int c  = n - kk * 768;
    unsigned short val = 0;
    if ((e >> 5) == kk) val = f2bf(w2[(size_t)e * 768 + c]);
    W2t[(size_t)n * 160 + e] = val;
}

// ---------------------------------------------------------------------------
// shift: xx = qshift(x)-x (f32), xxx = bf16(x + xx*maa_x)
// ---------------------------------------------------------------------------
__global__ __launch_bounds__(256) void shift_kernel(
    const float* __restrict__ x, const float* __restrict__ maa_x,
    float* __restrict__ xxO, unsigned short* __restrict__ xxxO)
{
    const int tok = blockIdx.x;
    const int t   = tok & (TT - 1);
    const int hh  = t >> 5;
    const int wp  = t & 31;
    const int tid = threadIdx.x;
    const float* xrow = x + (size_t)tok * CC;
    for (int c = tid; c < CC; c += 256) {
        float xc = xrow[c];
        float sh;
        if (c < 192)      sh = (wp > 0)  ? xrow[c - CC]      : 0.f;
        else if (c < 384) sh = (wp < 31) ? xrow[c + CC]      : 0.f;
        else if (c < 576) sh = (hh > 0)  ? xrow[c - 32 * CC] : 0.f;
        else              sh = (hh < 31) ? xrow[c + 32 * CC] : 0.f;
        float xxv = sh - xc;
        size_t o = (size_t)tok * CC + c;
        xxO[o]  = xxv;
        xxxO[o] = f2bf(fmaf(xxv, maa_x[c], xc));
    }
}

// ---------------------------------------------------------------------------
// bf16 MFMA GEMM, 64x64 tile (for small-N GEMMs).
// ---------------------------------------------------------------------------
template<int KDIM, class Epi>
__device__ __forceinline__ void gemm_core(const unsigned short* __restrict__ A,
                                          const unsigned short* __restrict__ W,
                                          int N, const Epi& epi)
{
    __shared__ __align__(16) unsigned short As[64][40];
    __shared__ __align__(16) unsigned short Bs[64][40];

    const int tid  = threadIdx.x;
    const int lane = tid & 63;
    const int wv   = tid >> 6;
    const int wm   = (wv >> 1) * 32, wn = (wv & 1) * 32;
    const int m0   = blockIdx.y * 64, n0 = blockIdx.x * 64;
    const int srow = tid >> 2, scb = (tid & 3) * 8;
    const int l15  = lane & 15, kb8 = (lane >> 4) * 8;

    f32x4 acc[2][2];
    #pragma unroll
    for (int a = 0; a < 2; ++a)
        #pragma unroll
        for (int b = 0; b < 2; ++b)
            #pragma unroll
            for (int e = 0; e < 4; ++e) acc[a][b][e] = 0.f;

    const unsigned short* aP = A + (size_t)(m0 + srow) * KDIM + scb;
    const unsigned short* bP = W + (size_t)(n0 + srow) * KDIM + scb;
    const bool bvalid = (n0 + srow) < N;

    for (int k0 = 0; k0 < KDIM; k0 += 32) {
        uint4 av = *(const uint4*)(aP + k0);
        uint4 bw = make_uint4(0u, 0u, 0u, 0u);
        if (bvalid) bw = *(const uint4*)(bP + k0);
        *(uint4*)&As[srow][scb] = av;
        *(uint4*)&Bs[srow][scb] = bw;
        __syncthreads();

        bf16x8 a0 = *(const bf16x8*)&As[wm + l15][kb8];
        bf16x8 a1 = *(const bf16x8*)&As[wm + 16 + l15][kb8];
        bf16x8 b0 = *(const bf16x8*)&Bs[wn + l15][kb8];
        bf16x8 b1 = *(const bf16x8*)&Bs[wn + 16 + l15][kb8];
        acc[0][0] = __builtin_amdgcn_mfma_f32_16x16x32_bf16(a0, b0, acc[0][0], 0, 0, 0);
        acc[0][1] = __builtin_amdgcn_mfma_f32_16x16x32_bf16(a0, b1, acc[0][1], 0, 0, 0);
        acc[1][0] = __builtin_amdgcn_mfma_f32_16x16x32_bf16(a1, b0, acc[1][0], 0, 0, 0);
        acc[1][1] = __builtin_amdgcn_mfma_f32_16x16x32_bf16(a1, b1, acc[1][1], 0, 0, 0);
        __syncthreads();
    }

    const int rb_ = m0 + wm + (lane >> 4) * 4;
    #pragma unroll
    for (int mi = 0; mi < 2; ++mi)
        #pragma unroll
        for (int ni = 0; ni < 2; ++ni) {
            int col = n0 + wn + ni * 16 + l15;
            if (col < N) {
                #pragma unroll
                for (int j = 0; j < 4; ++j)
                    epi(rb_ + mi * 16 + j, col, acc[mi][ni][j]);
            }
        }
}

// ---------------------------------------------------------------------------
// bf16 MFMA GEMM, 128x128 tile, 4 waves (each 64x64 = 4x4 frags), BK=32.
// global_load_lds (width 16) staging into linear [128][32] LDS; caller
// supplies m0/n0 (XCD-swizzled). Requires N % 128 == 0 tiles to be full
// on the staging path (epilogue still bounds-checks).
// ---------------------------------------------------------------------------
template<int KDIM, class Epi>
__device__ __forceinline__ void gemm_core128(const unsigned short* __restrict__ A,
                                             const unsigned short* __restrict__ W,
                                             int N, int m0, int n0, const Epi& epi)
{
    __shared__ __align__(16) unsigned short As[128][32];
    __shared__ __align__(16) unsigned short Bs[128][32];

    const int tid  = threadIdx.x;
    const int lane = tid & 63;
    const int wv   = tid >> 6;
    const int wm   = (wv >> 1) * 64, wn = (wv & 1) * 64;
    const int l15  = lane & 15, kb8 = (lane >> 4) * 8, rb4 = (lane >> 4) * 4;
    const int sr   = tid >> 2, sq = (tid & 3) * 8;  // staging: row 0..63, col-octet

    f32x4 acc[4][4];
    #pragma unroll
    for (int a = 0; a < 4; ++a)
        #pragma unroll
        for (int b = 0; b < 4; ++b)
            #pragma unroll
            for (int e = 0; e < 4; ++e) acc[a][b][e] = 0.f;

    const unsigned short* aP  = A + (size_t)(m0 + sr) * KDIM + sq;
    const unsigned short* aP2 = A + (size_t)(m0 + 64 + sr) * KDIM + sq;
    const unsigned short* bP  = W + (size_t)(n0 + sr) * KDIM + sq;
    const unsigned short* bP2 = W + (size_t)(n0 + 64 + sr) * KDIM + sq;
    unsigned short* asD  = &As[sr][sq];
    unsigned short* asD2 = &As[64 + sr][sq];
    unsigned short* bsD  = &Bs[sr][sq];
    unsigned short* bsD2 = &Bs[64 + sr][sq];

    for (int k0 = 0; k0 < KDIM; k0 += 32) {
        gload16(aP + k0,  asD);
        gload16(aP2 + k0, asD2);
        gload16(bP + k0,  bsD);
        gload16(bP2 + k0, bsD2);
        __syncthreads();   // drains vmcnt (incl. global_load_lds) before use

        bf16x8 af[4], bfr[4];
        #pragma unroll
        for (int mi = 0; mi < 4; ++mi)
            af[mi] = *(const bf16x8*)&As[wm + mi * 16 + l15][kb8];
        #pragma unroll
        for (int ni = 0; ni < 4; ++ni)
            bfr[ni] = *(const bf16x8*)&Bs[wn + ni * 16 + l15][kb8];
        #pragma unroll
        for (int mi = 0; mi < 4; ++mi)
            #pragma unroll
            for (int ni = 0; ni < 4; ++ni)
                acc[mi][ni] = __builtin_amdgcn_mfma_f32_16x16x32_bf16(af[mi], bfr[ni], acc[mi][ni], 0, 0, 0);
        __syncthreads();
    }

    const int rbase = m0 + wm + rb4;
    #pragma unroll
    for (int mi = 0; mi < 4; ++mi)
        #pragma unroll
        for (int ni = 0; ni < 4; ++ni) {
            int col = n0 + wn + ni * 16 + l15;
            if (col < N) {
                #pragma unroll
                for (int j = 0; j < 4; ++j)
                    epi(rbase + mi * 16 + j, col, acc[mi][ni][j]);
            }
        }
}

// Epilogues ----------------------------------------------------------------
struct EpiTanh {
    unsigned short* O; int ldo;
    __device__ void operator()(int r, int c, float v) const {
        O[(size_t)r * ldo + c] = f2bf(tanhf(v));
    }
};
struct EpiF32 {
    float* O;
    __device__ void operator()(int r, int c, float v) const {
        O[(size_t)r * 768 + c] = v;
    }
};
struct EpiDec {
    const float* td; float* O;
    __device__ void operator()(int r, int c, float v) const {
        O[(size_t)r * 768 + c] = expf(-expf(td[c] + v));
    }
};
struct EpiMix {
    const float* px; const float* pxx;
    const float* maa[5];
    unsigned short* outs[5];
    __device__ void operator()(int r, int c, float v) const {
        int kk = c / 768;
        int cc = c - kk * 768;
        size_t o = (size_t)r * 768 + cc;
        outs[kk][o] = f2bf(fmaf(pxx[o], maa[kk][cc] + v, px[o]));
    }
};
struct EpiRKVG {
    unsigned short* O; bool silu;
    __device__ void operator()(int r, int c, float v) const {
        if (silu) v = v / (1.f + expf(-v));
        O[(size_t)r * 768 + c] = f2bf(v);
    }
};

template<int KDIM, class Epi>
__global__ __launch_bounds__(256) void gemm_one(const unsigned short* __restrict__ A,
                                                const unsigned short* __restrict__ W,
                                                int N, Epi epi)
{
    gemm_core<KDIM>(A, W, N, epi);
}

// 1D grid, XCD-swizzled. NB = number of 128-col tiles (N/128).
template<int KDIM, int NB, class Epi>
__global__ __launch_bounds__(256) void gemm_one128(const unsigned short* __restrict__ A,
                                                   const unsigned short* __restrict__ W,
                                                   int N, Epi epi)
{
    const int idx = xcd_swz(blockIdx.x, gridDim.x);
    const int m0 = (idx / NB) * 128, n0 = (idx % NB) * 128;
    gemm_core128<KDIM>(A, W, N, m0, n0, epi);
}

struct QuadArgs {
    const unsigned short* A[4];
    const unsigned short* W[4];
    unsigned short* O[4];
};
// grid = 768 blocks 1D: idx -> (z, y, x); XCD chunk = 96 blocks = one z,
// 16 y-panels -> A-panel 3.1MB + W 1.2MB resident in that XCD's 4MB L2.
__global__ __launch_bounds__(256) void gemm_quad768(QuadArgs q)
{
    const int idx = xcd_swz(blockIdx.x, 768);
    const int z = idx / 192;
    const int rz = idx - z * 192;
    const int m0 = (rz / 6) * 128, n0 = (rz % 6) * 128;
    EpiRKVG e{q.O[z], z == 3};
    gemm_core128<768>(q.A[z], q.W[z], 768, m0, n0, e);
}

// ---------------------------------------------------------------------------
// WKV6 parallel chunked scan, 3 phases.
// ---------------------------------------------------------------------------
__global__ __launch_bounds__(256) void wkv_local(
    const unsigned short* __restrict__ r, const unsigned short* __restrict__ k,
    const unsigned short* __restrict__ v, const float* __restrict__ dec,
    const float* __restrict__ u, float* __restrict__ y,
    unsigned short* __restrict__ rsb, float* __restrict__ kvt,
    float* __restrict__ dcv)
{
    __shared__ __align__(16) unsigned short rwL[64][40], kwL[64][40];
    __shared__ __align__(16) unsigned short vT0[32][40], vT1[32][40];
    __shared__ __align__(16) unsigned short ksT0[32][40], ksT1[32][40];
    __shared__ __align__(16) unsigned short PL0[64][40], PL1[64][40];
    __shared__ float AL[65][32];
    __shared__ float segprod[8][32];
    __shared__ float dpart[64][4];
    __shared__ float diagL[64];
    __shared__ float uL[32];

    const int c   = blockIdx.x;
    const int bh  = blockIdx.y;
    const int b = bh / NH_, h = bh % NH_;
    const int tid  = threadIdx.x;
    const int lane = tid & 63;
    const int wv   = tid >> 6;
    const int l15  = lane & 15;
    const int kb8  = (lane >> 4) * 8;
    const int rb4  = (lane >> 4) * 4;
    const int tc   = c * CL;

    const size_t base0 = ((size_t)b * TT) * CC + (size_t)h * HS_;

    if (tid < 32) uL[tid] = u[h * HS_ + tid];

    const int lrow = tid >> 2, lq = (tid & 3) * 8;
    const int cj = tid & 31, cseg = tid >> 5;

    // ---- load r,k,v (v transposed) ----
    {
        size_t gp = base0 + (size_t)(tc + lrow) * CC + lq;
        uint4 rv = *(const uint4*)(r + gp);
        uint4 kv = *(const uint4*)(k + gp);
        uint4 vv = *(const uint4*)(v + gp);
        *(uint4*)&rwL[lrow][lq] = rv;
        *(uint4*)&kwL[lrow][lq] = kv;
        const unsigned short* vp = (const unsigned short*)&vv;
        if (lrow < 32) {
            #pragma unroll
            for (int e = 0; e < 8; ++e) vT0[lq + e][lrow] = vp[e];
        } else {
            #pragma unroll
            for (int e = 0; e < 8; ++e) vT1[lq + e][lrow - 32] = vp[e];
        }
    }
    // ---- decay loads + per-segment product ----
    float dv[8];
    #pragma unroll
    for (int q = 0; q < 8; ++q)
        dv[q] = dec[base0 + (size_t)(tc + cseg * 8 + q) * CC + cj];
    {
        float lp = dv[0];
        #pragma unroll
        for (int q = 1; q < 8; ++q) lp *= dv[q];
        segprod[cseg][cj] = lp;
    }
    __syncthreads();

    // ---- diag partials: sum_j r*u*k (raw r,k) ----
    {
        const int ptau = tid >> 2, pp = tid & 3;
        float acc = 0.f;
        #pragma unroll
        for (int e = 0; e < 8; ++e) {
            int j = pp * 8 + e;
            acc += bf2f(rwL[ptau][j]) * uL[j] * bf2f(kwL[ptau][j]);
        }
        dpart[ptau][pp] = acc;
    }
    // ---- cumprod: AL[tau][j]; AL[64][j] = full-chunk decay ----
    {
        float pre = 1.f;
        #pragma unroll
        for (int s = 0; s < 7; ++s) if (s < cseg) pre *= segprod[s][cj];
        float run = pre;
        #pragma unroll
        for (int q = 0; q < 8; ++q) {
            AL[cseg * 8 + q][cj] = run;
            run *= dv[q];
        }
        if (cseg == 7) AL[64][cj] = run;
    }
    __syncthreads();

    if (tid < 64)
        diagL[tid] = dpart[tid][0] + dpart[tid][1] + dpart[tid][2] + dpart[tid][3];
    if (tid < 32)
        dcv[((size_t)bh * NCH + c) * 32 + tid] = AL[64][tid];

    // ---- scale in place: r~ = r*A_tau, k~ = k/A_{tau+1} ----
    #pragma unroll
    for (int q = 0; q < 8; ++q) {
        int tau = cseg * 8 + q;
        float a  = AL[tau][cj];
        float ia = 1.f / AL[tau + 1][cj];
        unsigned short rs = f2bf(bf2f(rwL[tau][cj]) * a);
        unsigned short ks = f2bf(bf2f(kwL[tau][cj]) * ia);
        rwL[tau][cj] = rs;
        kwL[tau][cj] = ks;
        if (tau < 32) ksT0[cj][tau] = ks; else ksT1[cj][tau - 32] = ks;
    }
    __syncthreads();

    // ---- Q = R~ @ K~^T (wave quadrant 32x32), mask -> PL ----
    {
        const int wm = (wv >> 1) * 32, wn = (wv & 1) * 32;
        bf16x8 a0 = *(const bf16x8*)&rwL[wm + l15][kb8];
        bf16x8 a1 = *(const bf16x8*)&rwL[wm + 16 + l15][kb8];
        bf16x8 b0 = *(const bf16x8*)&kwL[wn + l15][kb8];
        bf16x8 b1 = *(const bf16x8*)&kwL[wn + 16 + l15][kb8];
        f32x4 qf[2][2];
        #pragma unroll
        for (int mi = 0; mi < 2; ++mi)
            #pragma unroll
            for (int ni = 0; ni < 2; ++ni)
                #pragma unroll
                for (int e = 0; e < 4; ++e) qf[mi][ni][e] = 0.f;
        qf[0][0] = __builtin_amdgcn_mfma_f32_16x16x32_bf16(a0, b0, qf[0][0], 0, 0, 0);
        qf[0][1] = __builtin_amdgcn_mfma_f32_16x16x32_bf16(a0, b1, qf[0][1], 0, 0, 0);
        qf[1][0] = __builtin_amdgcn_mfma_f32_16x16x32_bf16(a1, b0, qf[1][0], 0, 0, 0);
        qf[1][1] = __builtin_amdgcn_mfma_f32_16x16x32_bf16(a1, b1, qf[1][1], 0, 0, 0);
        #pragma unroll
        for (int mi = 0; mi < 2; ++mi)
            #pragma unroll
            for (int ni = 0; ni < 2; ++ni) {
                const int col = wn + ni * 16 + l15;
                #pragma unroll
                for (int jj = 0; jj < 4; ++jj) {
                    const int row = wm + mi * 16 + rb4 + jj;
                    float val = (col < row) ? qf[mi][ni][jj]
                              : ((col == row) ? diagL[row] : 0.f);
                    unsigned short bvv = f2bf(val);
                    if (col < 32) PL0[row][col] = bvv;
                    else          PL1[row][col - 32] = bvv;
                }
            }
    }
    __syncthreads();

    // ---- emit r~ to global (phase-3 input) ----
    *(uint4*)(rsb + base0 + (size_t)(tc + lrow) * CC + lq) = *(const uint4*)&rwL[lrow][lq];

    // ---- y_loc = P @ V (wave rows [16w,16w+16)) ----
    {
        const int mr = wv * 16;
        bf16x8 pa0 = *(const bf16x8*)&PL0[mr + l15][kb8];
        bf16x8 pa1 = *(const bf16x8*)&PL1[mr + l15][kb8];
        #pragma unroll
        for (int ni = 0; ni < 2; ++ni) {
            bf16x8 bv0 = *(const bf16x8*)&vT0[ni * 16 + l15][kb8];
            bf16x8 bv1 = *(const bf16x8*)&vT1[ni * 16 + l15][kb8];
            f32x4 acc;
            #pragma unroll
            for (int e = 0; e < 4; ++e) acc[e] = 0.f;
            acc = __builtin_amdgcn_mfma_f32_16x16x32_bf16(pa0, bv0, acc, 0, 0, 0);
            acc = __builtin_amdgcn_mfma_f32_16x16x32_bf16(pa1, bv1, acc, 0, 0, 0);
            #pragma unroll
            for (int jj = 0; jj < 4; ++jj)
                y[base0 + (size_t)(tc + mr + rb4 + jj) * CC + ni * 16 + l15] = acc[jj];
        }
    }

    // ---- KVT_c = V^T @ K~ (32x32) -> global f32 ----
    {
        const int mi_ = (wv >> 1) * 16, nj = (wv & 1) * 16;
        bf16x8 av0 = *(const bf16x8*)&vT0[mi_ + l15][kb8];
        bf16x8 av1 = *(const bf16x8*)&vT1[mi_ + l15][kb8];
        bf16x8 bk0 = *(const bf16x8*)&ksT0[nj + l15][kb8];
        bf16x8 bk1 = *(const bf16x8*)&ksT1[nj + l15][kb8];
        f32x4 acc;
        #pragma unroll
        for (int e = 0; e < 4; ++e) acc[e] = 0.f;
        acc = __builtin_amdgcn_mfma_f32_16x16x32_bf16(av0, bk0, acc, 0, 0, 0);
        acc = __builtin_amdgcn_mfma_f32_16x16x32_bf16(av1, bk1, acc, 0, 0, 0);
        const int j = nj + l15;
        const size_t sb = ((size_t)bh * NCH + c) << 10;
        #pragma unroll
        for (int jj = 0; jj < 4; ++jj)
            kvt[sb + (size_t)(mi_ + rb4 + jj) * 32 + j] = acc[jj];
    }
}

// ---------------------------------------------------------------------------
// Phase 2: serial scan over 16 chunks. S = D_c*(S + KVT_c).
// ---------------------------------------------------------------------------
__global__ __launch_bounds__(256) void wkv_carry(
    const float* __restrict__ kvt, const float* __restrict__ dcv,
    unsigned short* __restrict__ spv)
{
    const int bh = blockIdx.x;
    const int tid = threadIdx.x;
    const int e0 = tid << 2;
    const int j0 = e0 & 31;
    float s0 = 0.f, s1 = 0.f, s2 = 0.f, s3 = 0.f;
    #pragma unroll
    for (int c = 0; c < NCH; ++c) {
        const size_t sb = (size_t)bh * NCH + c;
        float4 kv = *(const float4*)(kvt + (sb << 10) + e0);
        float4 d4 = *(const float4*)(dcv + sb * 32 + j0);
        s0 = d4.x * (s0 + kv.x);
        s1 = d4.y * (s1 + kv.y);
        s2 = d4.z * (s2 + kv.z);
        s3 = d4.w * (s3 + kv.w);
        if (c < NCH - 1) {
            unsigned lo = (unsigned)f2bf(s0) | ((unsigned)f2bf(s1) << 16);
            unsigned hi = (unsigned)f2bf(s2) | ((unsigned)f2bf(s3) << 16);
            *(uint2*)(spv + ((sb + 1) << 10) + e0) = make_uint2(lo, hi);
        }
    }
}

// ---------------------------------------------------------------------------
// Phase 3: y += R~ @ Sprev^T per chunk (chunks 1..15).
// ---------------------------------------------------------------------------
__global__ __launch_bounds__(256) void wkv_stadd(
    const unsigned short* __restrict__ rsb, const unsigned short* __restrict__ spv,
    float* __restrict__ y)
{
    __shared__ __align__(16) unsigned short rsL[64][40];
    __shared__ __align__(16) unsigned short STb[32][40];

    const int c  = blockIdx.x + 1;
    const int bh = blockIdx.y;
    const int b = bh / NH_, h = bh % NH_;
    const int tid = threadIdx.x, lane = tid & 63, wv = tid >> 6;
    const int l15 = lane & 15, kb8 = (lane >> 4) * 8, rb4 = (lane >> 4) * 4;
    const int tc = c * CL;
    const size_t base0 = ((size_t)b * TT) * CC + (size_t)h * HS_;
    const int lrow = tid >> 2, lq = (tid & 3) * 8;

    *(uint4*)&rsL[lrow][lq] = *(const uint4*)(rsb + base0 + (size_t)(tc + lrow) * CC + lq);
    if (tid < 128) {
        int row = tid >> 2, q = (tid & 3) * 8;
        *(uint4*)&STb[row][q] =
            *(const uint4*)(spv + (((size_t)bh * NCH + c) << 10) + (size_t)row * 32 + q);
    }
    __syncthreads();

    const int mr = wv * 16;
    bf16x8 ra = *(const bf16x8*)&rsL[mr + l15][kb8];
    #pragma unroll
    for (int ni = 0; ni < 2; ++ni) {
        bf16x8 bs = *(const bf16x8*)&STb[ni * 16 + l15][kb8];
        f32x4 acc;
        #pragma unroll
        for (int e = 0; e < 4; ++e) acc[e] = 0.f;
        acc = __builtin_amdgcn_mfma_f32_16x16x32_bf16(ra, bs, acc, 0, 0, 0);
        #pragma unroll
        for (int jj = 0; jj < 4; ++jj) {
            size_t gp = base0 + (size_t)(tc + mr + rb4 + jj) * CC + ni * 16 + l15;
            y[gp] += acc[jj];
        }
    }
}

// ---------------------------------------------------------------------------
// LayerNorm(y) * g -> bf16 z
// ---------------------------------------------------------------------------
__global__ __launch_bounds__(256) void ln_gate(
    const float* __restrict__ y, const unsigned short* __restrict__ g,
    const float* __restrict__ lnw, const float* __restrict__ lnb,
    unsigned short* __restrict__ z)
{
    __shared__ float sy[CC];
    __shared__ float rbuf[8];
    __shared__ float stats[2];

    const int row = blockIdx.x, tid = threadIdx.x;
    const float* yr = y + (size_t)row * CC;

    float s1 = 0.f, s2 = 0.f;
    #pragma unroll
    for (int q = 0; q < 3; ++q) {
        int c = tid + q * 256;
        float vv = yr[c];
        sy[c] = vv;
        s1 += vv;
        s2 += vv * vv;
    }
    #pragma unroll
    for (int off = 32; off > 0; off >>= 1) {
        s1 += __shfl_down(s1, off);
        s2 += __shfl_down(s2, off);
    }
    const int wid = tid >> 6;
    if ((tid & 63) == 0) { rbuf[wid] = s1; rbuf[4 + wid] = s2; }
    __syncthreads();
    if (tid == 0) {
        float S1 = rbuf[0] + rbuf[1] + rbuf[2] + rbuf[3];
        float S2 = rbuf[4] + rbuf[5] + rbuf[6] + rbuf[7];
        float mu = S1 / (float)CC;
        float var = S2 / (float)CC - mu * mu;
        stats[0] = mu;
        stats[1] = rsqrtf(var + 1e-5f);
    }
    __syncthreads();
    const float mu = stats[0], rstd = stats[1];
    const unsigned short* gr = g + (size_t)row * CC;
    unsigned short* zr = z + (size_t)row * CC;
    #pragma unroll
    for (int q = 0; q < 3; ++q) {
        int c = tid + q * 256;
        zr[c] = f2bf(fmaf((sy[c] - mu) * rstd, lnw[c], lnb[c]) * bf2f(gr[c]));
    }
}

// ---------------------------------------------------------------------------
extern "C" void kernel_launch(void* const* d_in, const int* in_sizes, int n_in,
                              void* d_out, int out_size, void* d_ws, size_t ws_size,
                              hipStream_t stream)
{
    const float* x      = (const float*)d_in[0];
    const float* maa_x  = (const float*)d_in[1];
    const float* maa_w  = (const float*)d_in[2];
    const float* maa_k  = (const float*)d_in[3];
    const float* maa_v  = (const float*)d_in[4];
    const float* maa_r  = (const float*)d_in[5];
    const float* maa_g  = (const float*)d_in[6];
    const float* w1     = (const float*)d_in[7];
    const float* w2     = (const float*)d_in[8];
    const float* tdec   = (const float*)d_in[9];
    const float* tdw1   = (const float*)d_in[10];
    const float* tdw2   = (const float*)d_in[11];
    const float* faaaa  = (const float*)d_in[12];
    const float* Wr     = (const float*)d_in[13];
    const float* Wk     = (const float*)d_in[14];
    const float* Wv     = (const float*)d_in[15];
    const float* Wg     = (const float*)d_in[16];
    const float* Wo     = (const float*)d_in[17];
    const float* lnw    = (const float*)d_in[18];
    const float* lnb    = (const float*)d_in[19];

    char* base = (char*)d_ws;
    size_t off = 0;
    auto alloc = [&](size_t bytes) -> char* {
        char* p = base + off;
        off = (off + bytes + 255) & ~(size_t)255;
        return p;
    };

    float*          xx   = (float*)alloc(SZ * 4);           // later reused as y
    float*          decb = (float*)alloc(SZ * 4);
    unsigned short* xxx  = (unsigned short*)alloc(SZ * 2);  // later reused as z
    unsigned short* xw   = (unsigned short*)alloc(SZ * 2);
    unsigned short* xk   = (unsigned short*)alloc(SZ * 2);  // later reused as kvtb
    unsigned short* xv   = (unsigned short*)alloc(SZ * 2);  // later reused as spvb
    unsigned short* xr   = (unsigned short*)alloc(SZ * 2);  // later reused as rsb
    unsigned short* xg   = (unsigned short*)alloc(SZ * 2);  // later reused as dcb
    unsigned short* rb   = (unsigned short*)alloc(SZ * 2);
    unsigned short* kb   = (unsigned short*)alloc(SZ * 2);
    unsigned short* vb   = (unsigned short*)alloc(SZ * 2);
    unsigned short* gb   = (unsigned short*)alloc(SZ * 2);
    unsigned short* t5   = (unsigned short*)alloc((size_t)4096 * 160 * 2);
    unsigned short* d1   = (unsigned short*)alloc((size_t)4096 * 64 * 2);
    unsigned short* w1t  = (unsigned short*)alloc((size_t)160 * 768 * 2);
    unsigned short* w2t  = (unsigned short*)alloc((size_t)3840 * 160 * 2);
    unsigned short* wrt  = (unsigned short*)alloc((size_t)768 * 768 * 2);
    unsigned short* wkt  = (unsigned short*)alloc((size_t)768 * 768 * 2);
    unsigned short* wvt  = (unsigned short*)alloc((size_t)768 * 768 * 2);
    unsigned short* wgt  = (unsigned short*)alloc((size_t)768 * 768 * 2);
    unsigned short* wot  = (unsigned short*)alloc((size_t)768 * 768 * 2);
    unsigned short* td1t = (unsigned short*)alloc((size_t)64 * 768 * 2);
    unsigned short* td2t = (unsigned short*)alloc((size_t)768 * 64 * 2);

    float*          y    = xx;                      // xx dead after mixall
    unsigned short* z    = xxx;                     // xxx dead after t5 GEMM
    unsigned short* rsb  = xr;
    float*          kvtb = (float*)xk;
    unsigned short* spvb = xv;
    float*          dcb  = (float*)xg;

    // 1) weight prep
    TArgs ta = {{
        { w1,   w1t,  768, 160 },
        { Wr,   wrt,  768, 768 },
        { Wk,   wkt,  768, 768 },
        { Wv,   wvt,  768, 768 },
        { Wg,   wgt,  768, 768 },
        { Wo,   wot,  768, 768 },
        { tdw1, td1t, 768, 64  },
        { tdw2, td2t, 64,  768 },
    }};
    transpose_cast<<<dim3(24, 24, 8), 256, 0, stream>>>(ta);
    w2fill<<<3840, 192, 0, stream>>>(w2, w2t);

    // 2) shift + xxx
    shift_kernel<<<BB * TT, 256, 0, stream>>>(x, maa_x, xx, xxx);

    // 3) t5 = tanh(xxx @ w1)           (M=4096, K=768, N=160) 64-tile
    gemm_one<768, EpiTanh><<<dim3(3, 64), 256, 0, stream>>>(xxx, w1t, 160, EpiTanh{t5, 160});

    // 4) mixall: t5 @ blockdiag(w2)    (K=160, N=3840) 128-tile, swizzled
    EpiMix em{ x, xx,
               { maa_w, maa_k, maa_v, maa_r, maa_g },
               { xw, xk, xv, xr, xg } };
    gemm_one128<160, 30, EpiMix><<<960, 256, 0, stream>>>(t5, w2t, 3840, em);

    // 5) d1 = tanh(xw @ tdw1)          (K=768, N=64) 64-tile
    gemm_one<768, EpiTanh><<<dim3(1, 64), 256, 0, stream>>>(xw, td1t, 64, EpiTanh{d1, 64});

    // 6) dec = exp(-exp(tdecay + d1 @ tdw2))   (K=64, N=768) 64-tile
    gemm_one<64, EpiDec><<<dim3(12, 64), 256, 0, stream>>>(d1, td2t, 768, EpiDec{tdec, decb});

    // 7) r,k,v,g GEMMs (128-tile, gload_lds, XCD-swizzled; silu on g)
    QuadArgs qa = {{ xr, xk, xv, xg }, { wrt, wkt, wvt, wgt }, { rb, kb, vb, gb }};
    gemm_quad768<<<768, 256, 0, stream>>>(qa);

    // 8) WKV parallel chunked scan
    wkv_local<<<dim3(NCH, NBH), 256, 0, stream>>>(rb, kb, vb, decb, faaaa, y, rsb, kvtb, dcb);
    wkv_carry<<<NBH, 256, 0, stream>>>(kvtb, dcb, spvb);
    wkv_stadd<<<dim3(NCH - 1, NBH), 256, 0, stream>>>(rsb, spvb, y);

    // 9) LayerNorm * gate -> z (bf16)
    ln_gate<<<BB * TT, 256, 0, stream>>>(y, gb, lnw, lnb, z);

    // 10) out = z @ Wo (f32 out) 128-tile, swizzled
    gemm_one128<768, 6, EpiF32><<<192, 256, 0, stream>>>(z, wot, 768, EpiF32{(float*)d_out});
}